// Round 8
// baseline (1610.558 us; speedup 1.0000x reference)
//
#include <hip/hip_runtime.h>

typedef __bf16 bf16;
typedef __bf16 bf16x8 __attribute__((ext_vector_type(8)));
typedef float f32x4 __attribute__((ext_vector_type(4)));

#define B_ 2
#define S_ 2048
#define D_ 512
#define H_ 8

// fp32 -> bf16 hi + bf16 lo residual (split precision)
__global__ __launch_bounds__(256) void split_f32(const float* __restrict__ src,
                                                 bf16* __restrict__ hi, bf16* __restrict__ lo,
                                                 long n) {
  long i = (long)blockIdx.x * 256 + threadIdx.x;
  if (i >= n) return;
  float v = src[i];
  bf16 h = (bf16)v;
  hi[i] = h;
  lo[i] = (bf16)(v - (float)h);
}

// [z][R][C] fp32 -> [z][C][R] bf16 hi (+ optional lo residual plane)
__global__ __launch_bounds__(256) void transpose_f32(const float* __restrict__ src,
                                                     bf16* __restrict__ hi, bf16* __restrict__ lo,
                                                     int R, int C) {
  __shared__ float t[32][33];
  size_t zoff = (size_t)blockIdx.z * R * C;
  const float* s = src + zoff;
  int tx = threadIdx.x;  // 0..31
  int ty = threadIdx.y;  // 0..7
  int c0 = blockIdx.x * 32, r0 = blockIdx.y * 32;
#pragma unroll
  for (int i = 0; i < 4; ++i)
    t[ty + i * 8][tx] = s[(size_t)(r0 + ty + i * 8) * C + c0 + tx];
  __syncthreads();
#pragma unroll
  for (int i = 0; i < 4; ++i) {
    float v = t[tx][ty + i * 8];
    size_t o = zoff + (size_t)(c0 + ty + i * 8) * R + r0 + tx;
    bf16 h = (bf16)v;
    hi[o] = h;
    if (lo) lo[o] = (bf16)(v - (float)h);
  }
}

// Generalized batched GEMM args. blockIdx.z -> zi = zbase+z; decode
// p = zi/PBG, b = (zi%PBG)/NG, g = zi%NG; operand offset = p*sXp+b*sXb+g*sXg+z*sXz.
struct GemmArgs {
  const bf16 *A, *Alo, *Bm, *Blo;
  void* C; bf16* Clo;
  const float* bias;
  int K, lda, ldb, ldc;
  int zbase, NG, PBG;
  long sAp, sAb, sAg, sAz;
  long sBp, sBb, sBg, sBz;
  long sCp, sCb, sCg, sCz;
  long sbp, sbb, sbg, sbz;
};

// NT GEMM: C[m][n] = sum_k A[m][k]*B[n][k]. BIAS: 0=none,1=bias[n],2=bias[m].
// SIN: A,B have lo residual planes -> 3-term split MFMA (near-fp32 product).
// SOUT: emit bf16 hi plane to C and bf16 residual plane to Clo.
template <typename OutT, int BIAS, bool SIN, bool SOUT>
__global__ __launch_bounds__(256) void gemm_nt(GemmArgs p) {
  int zloc = blockIdx.z;
  int zi = p.zbase + zloc;
  int pp = zi / p.PBG; int rz = zi - pp * p.PBG;
  int bb = rz / p.NG;  int g = rz - bb * p.NG;
  long offA = pp * p.sAp + bb * p.sAb + g * p.sAg + (long)zloc * p.sAz;
  long offB = pp * p.sBp + bb * p.sBb + g * p.sBg + (long)zloc * p.sBz;
  long offC = pp * p.sCp + bb * p.sCb + g * p.sCg + (long)zloc * p.sCz;
  const bf16* A  = p.A + offA;
  const bf16* Bm = p.Bm + offB;
  const bf16* Al = SIN ? (p.Alo + offA) : nullptr;
  const bf16* Bl = SIN ? (p.Blo + offB) : nullptr;
  OutT* C = (OutT*)p.C + offC;
  bf16* Cl = SOUT ? (p.Clo + offC) : nullptr;
  const float* bias = nullptr;
  if (BIAS) bias = p.bias + (pp * p.sbp + bb * p.sbb + g * p.sbg + (long)zloc * p.sbz);

  extern __shared__ bf16 sm[];
  bf16* lA  = sm;
  bf16* lB  = sm + 4096;
  bf16* lAl = sm + 8192;
  bf16* lBl = sm + 12288;

  int tid = threadIdx.x;
  int lane = tid & 63;
  int w = tid >> 6;
  int wm = (w >> 1) << 6;   // wave's 64-row origin in 128-tile
  int wn = (w & 1) << 6;    // wave's 64-col origin
  long bm = (long)blockIdx.y * 128;
  long bn = (long)blockIdx.x * 128;

  f32x4 acc[4][4] = {};
  int qd = lane >> 4;   // k-chunk selector
  int fr = lane & 15;   // row (A) / col (B) within 16-tile

  // staging: LDS chunk q holds global (row r=q>>2, k-chunk c=(q&3)^(r&3))
  int r0s = tid >> 2,         c0s = (tid & 3) ^ (r0s & 3);
  int r1s = (tid + 256) >> 2, c1s = ((tid + 256) & 3) ^ (r1s & 3);

  for (int k0 = 0; k0 < p.K; k0 += 32) {
    long oa0 = (bm + r0s) * (long)p.lda + (k0 + c0s * 8);
    long oa1 = (bm + r1s) * (long)p.lda + (k0 + c1s * 8);
    long ob0 = (bn + r0s) * (long)p.ldb + (k0 + c0s * 8);
    long ob1 = (bn + r1s) * (long)p.ldb + (k0 + c1s * 8);
    bf16x8 a0 = *(const bf16x8*)(A + oa0);
    bf16x8 a1 = *(const bf16x8*)(A + oa1);
    bf16x8 b0 = *(const bf16x8*)(Bm + ob0);
    bf16x8 b1 = *(const bf16x8*)(Bm + ob1);
    bf16x8 al0, al1, bl0, bl1;
    if (SIN) {
      al0 = *(const bf16x8*)(Al + oa0); al1 = *(const bf16x8*)(Al + oa1);
      bl0 = *(const bf16x8*)(Bl + ob0); bl1 = *(const bf16x8*)(Bl + ob1);
    }
    __syncthreads();  // previous iteration's fragment reads complete
    *(bf16x8*)(lA + (size_t)tid * 8)         = a0;
    *(bf16x8*)(lA + (size_t)(tid + 256) * 8) = a1;
    *(bf16x8*)(lB + (size_t)tid * 8)         = b0;
    *(bf16x8*)(lB + (size_t)(tid + 256) * 8) = b1;
    if (SIN) {
      *(bf16x8*)(lAl + (size_t)tid * 8)         = al0;
      *(bf16x8*)(lAl + (size_t)(tid + 256) * 8) = al1;
      *(bf16x8*)(lBl + (size_t)tid * 8)         = bl0;
      *(bf16x8*)(lBl + (size_t)(tid + 256) * 8) = bl1;
    }
    __syncthreads();

    bf16x8 ah[4], bh[4], alv[4], blv[4];
#pragma unroll
    for (int i = 0; i < 4; ++i) {
      int m = wm + i * 16 + fr;
      size_t ia = ((size_t)m * 4 + (qd ^ (m & 3))) * 8;
      ah[i] = *(const bf16x8*)(lA + ia);
      if (SIN) alv[i] = *(const bf16x8*)(lAl + ia);
      int n = wn + i * 16 + fr;
      size_t ib = ((size_t)n * 4 + (qd ^ (n & 3))) * 8;
      bh[i] = *(const bf16x8*)(lB + ib);
      if (SIN) blv[i] = *(const bf16x8*)(lBl + ib);
    }
#pragma unroll
    for (int i = 0; i < 4; ++i)
#pragma unroll
      for (int j = 0; j < 4; ++j) {
        if (SIN) {
          acc[i][j] = __builtin_amdgcn_mfma_f32_16x16x32_bf16(alv[i], bh[j], acc[i][j], 0, 0, 0);
          acc[i][j] = __builtin_amdgcn_mfma_f32_16x16x32_bf16(ah[i], blv[j], acc[i][j], 0, 0, 0);
        }
        acc[i][j] = __builtin_amdgcn_mfma_f32_16x16x32_bf16(ah[i], bh[j], acc[i][j], 0, 0, 0);
      }
  }

  int rr0 = (lane >> 4) * 4;
#pragma unroll
  for (int i = 0; i < 4; ++i) {
#pragma unroll
    for (int j = 0; j < 4; ++j) {
#pragma unroll
      for (int r = 0; r < 4; ++r) {
        long row = bm + wm + i * 16 + rr0 + r;
        long col = bn + wn + j * 16 + fr;
        float v = acc[i][j][r];
        if (BIAS == 1) v += bias[col];
        if (BIAS == 2) v += bias[row];
        long idx = row * (long)p.ldc + col;
        if (SOUT) {
          bf16 h = (bf16)v;
          ((bf16*)C)[idx] = h;
          Cl[idx] = (bf16)(v - (float)h);
        } else {
          C[idx] = (OutT)v;
        }
      }
    }
  }
}

// one block per row of 2048 fp32 scores -> bf16 probabilities
__global__ __launch_bounds__(256) void softmax_kernel(const float* __restrict__ src,
                                                      bf16* __restrict__ dst, int n) {
  size_t row = blockIdx.x;
  const float* s = src + row * (size_t)n;
  bf16* d = dst + row * (size_t)n;
  int t = threadIdx.x;
  float4 v0 = ((const float4*)s)[t * 2];
  float4 v1 = ((const float4*)s)[t * 2 + 1];
  float e[8] = {v0.x, v0.y, v0.z, v0.w, v1.x, v1.y, v1.z, v1.w};
  float m = e[0];
#pragma unroll
  for (int i = 1; i < 8; ++i) m = fmaxf(m, e[i]);
#pragma unroll
  for (int off = 32; off >= 1; off >>= 1) m = fmaxf(m, __shfl_xor(m, off, 64));
  __shared__ float smm[4];
  __shared__ float ss[4];
  int w = t >> 6;
  if ((t & 63) == 0) smm[w] = m;
  __syncthreads();
  m = fmaxf(fmaxf(smm[0], smm[1]), fmaxf(smm[2], smm[3]));
  float sum = 0.f;
#pragma unroll
  for (int i = 0; i < 8; ++i) { e[i] = __expf(e[i] - m); sum += e[i]; }
#pragma unroll
  for (int off = 32; off >= 1; off >>= 1) sum += __shfl_xor(sum, off, 64);
  if ((t & 63) == 0) ss[w] = sum;
  __syncthreads();
  sum = ss[0] + ss[1] + ss[2] + ss[3];
  float inv = 1.0f / sum;
  bf16x8 ov;
#pragma unroll
  for (int i = 0; i < 8; ++i) ov[i] = (bf16)(e[i] * inv);
  *(bf16x8*)(d + t * 8) = ov;
}

extern "C" void kernel_launch(void* const* d_in, const int* in_sizes, int n_in,
                              void* d_out, int out_size, void* d_ws, size_t ws_size,
                              hipStream_t stream) {
  const float* x  = (const float*)d_in[0];
  const float* Wq = (const float*)d_in[1];
  const float* bq = (const float*)d_in[2];
  const float* Wk = (const float*)d_in[3];
  const float* bk = (const float*)d_in[4];
  const float* Wv = (const float*)d_in[5];
  const float* bv = (const float*)d_in[6];
  const float* Wo = (const float*)d_in[7];
  const float* bo = (const float*)d_in[8];
  float* out = (float*)d_out;  // output is fp32 (reference dtype)

  auto al = [](size_t v) { return (v + 255) & ~(size_t)255; };
  const size_t eX = (size_t)B_ * S_ * D_;   // 2M elements
  const size_t eW = (size_t)H_ * D_ * D_;   // 2M
  const size_t eSS = (size_t)S_ * S_;       // 4M
  const long SD = (long)S_ * D_;
  const long DD = (long)D_ * D_;
  const long DS = (long)D_ * S_;

  size_t fixed = 2 * al(eX * 2)            // xhi, xlo
               + 2 * al(2 * eW * 2)        // wqk hi, lo
               + al(eW * 2) + al(eW * 2)   // wv, wo
               + al(2ULL * H_ * D_ * 4);   // bqk fp32
  // config ladder: NB batches, GH heads, GS score-instances materialized
  int NB = 1, GH = 1, GS = 1; bool found = false;
  for (int nb = 2; nb >= 1 && !found; --nb)
    for (int gh = 8; gh >= 1 && !found; gh >>= 1)
      for (int gs = nb * gh; gs >= 1 && !found; gs >>= 1) {
        size_t need = fixed + al((size_t)nb * S_ * H_ * D_ * 2)
                    + 2 * al(2ULL * nb * gh * S_ * D_ * 2)
                    + al((size_t)nb * gh * D_ * S_ * 2)
                    + al((size_t)gs * eSS * 4) + al((size_t)gs * eSS * 2);
        if (need <= ws_size) { NB = nb; GH = gh; GS = gs; found = true; }
      }

  char* p0 = (char*)d_ws;
  size_t off = 0;
  bf16* xhi   = (bf16*)(p0 + off); off += al(eX * 2);
  bf16* xlo   = (bf16*)(p0 + off); off += al(eX * 2);
  bf16* wqkhi = (bf16*)(p0 + off); off += al(2 * eW * 2);   // [2H][e][d]
  bf16* wqklo = (bf16*)(p0 + off); off += al(2 * eW * 2);
  bf16* wvhi  = (bf16*)(p0 + off); off += al(eW * 2);       // [h][e][d]
  bf16* wohi  = (bf16*)(p0 + off); off += al(eW * 2);       // [e][h*D+d]
  float* bqk  = (float*)(p0 + off); off += al(2ULL * H_ * D_ * 4);
  bf16* catb  = (bf16*)(p0 + off); off += al((size_t)NB * S_ * H_ * D_ * 2);
  bf16* qkhi  = (bf16*)(p0 + off); off += al(2ULL * NB * GH * S_ * D_ * 2);  // [p][b][g][s][e]
  bf16* qklo  = (bf16*)(p0 + off); off += al(2ULL * NB * GH * S_ * D_ * 2);
  bf16* vT    = (bf16*)(p0 + off); off += al((size_t)NB * GH * D_ * S_ * 2); // [b][g][e][t]
  float* scores = (float*)(p0 + off); off += al((size_t)GS * eSS * 4);
  bf16* P     = (bf16*)(p0 + off);

  // ---- prep: split x, transpose+split weights, gather biases ----
  split_f32<<<dim3((unsigned)((eX + 255) / 256)), 256, 0, stream>>>(x, xhi, xlo, (long)eX);
  dim3 tb(32, 8, 1);
  transpose_f32<<<dim3(16, 16, H_), tb, 0, stream>>>(Wq, wqkhi, wqklo, D_, D_);
  transpose_f32<<<dim3(16, 16, H_), tb, 0, stream>>>(Wk, wqkhi + eW, wqklo + eW, D_, D_);
  transpose_f32<<<dim3(16, 16, H_), tb, 0, stream>>>(Wv, wvhi, nullptr, D_, D_);
  transpose_f32<<<dim3(16, 128, 1), tb, 0, stream>>>(Wo, wohi, nullptr, H_ * D_, D_);
  hipMemcpyAsync(bqk, bq, (size_t)H_ * D_ * 4, hipMemcpyDeviceToDevice, stream);
  hipMemcpyAsync(bqk + H_ * D_, bk, (size_t)H_ * D_ * 4, hipMemcpyDeviceToDevice, stream);

  for (int b0 = 0; b0 < B_; b0 += NB) {
    for (int h0 = 0; h0 < H_; h0 += GH) {
      {  // Q+K projections, one dispatch: z=(p,b,g), split-in split-out
        GemmArgs a{};
        a.A = xhi + (long)b0 * SD; a.Alo = xlo + (long)b0 * SD;
        a.Bm = wqkhi + (long)h0 * DD; a.Blo = wqklo + (long)h0 * DD;
        a.C = qkhi; a.Clo = qklo; a.bias = bqk + (long)h0 * D_;
        a.K = D_; a.lda = D_; a.ldb = D_; a.ldc = D_;
        a.zbase = 0; a.NG = GH; a.PBG = NB * GH;
        a.sAb = SD;
        a.sBp = (long)H_ * DD; a.sBg = DD;
        a.sCz = SD;
        a.sbp = (long)H_ * D_; a.sbg = D_;
        gemm_nt<bf16, 1, true, true><<<dim3(4, 16, 2 * NB * GH), 256, 32768, stream>>>(a);
      }
      {  // V^T: vT[b][g][e][t] = WvT[h]·x^T + bv (plain bf16)
        GemmArgs a{};
        a.A = wvhi + (long)h0 * DD; a.Bm = xhi + (long)b0 * SD;
        a.C = vT; a.bias = bv + (long)h0 * D_;
        a.K = D_; a.lda = D_; a.ldb = D_; a.ldc = S_;
        a.zbase = 0; a.NG = GH; a.PBG = NB * GH;
        a.sAg = DD;
        a.sBb = SD;
        a.sCz = DS;
        a.sbg = D_;
        gemm_nt<bf16, 2, false, false><<<dim3(16, 4, NB * GH), 256, 16384, stream>>>(a);
      }
      for (int g0 = 0; g0 < NB * GH; g0 += GS) {
        {  // scores = Q·K^T (split-in, fp32 out)
          GemmArgs a{};
          a.A = qkhi + (long)g0 * SD;  a.Alo = qklo + (long)g0 * SD;
          a.Bm = qkhi + ((long)NB * GH + g0) * SD;
          a.Blo = qklo + ((long)NB * GH + g0) * SD;
          a.C = scores;
          a.K = D_; a.lda = D_; a.ldb = D_; a.ldc = S_;
          a.zbase = g0; a.NG = GH; a.PBG = NB * GH;
          a.sAz = SD; a.sBz = SD; a.sCz = (long)eSS;
          gemm_nt<float, 0, true, false><<<dim3(16, 16, GS), 256, 32768, stream>>>(a);
        }
        softmax_kernel<<<dim3(GS * S_), 256, 0, stream>>>(scores, P, S_);
        {  // catb[b][s][(h0+g)*D+e] = P·vT^T
          GemmArgs a{};
          a.A = P; a.Bm = vT + (long)g0 * DS;
          a.C = catb + (long)h0 * D_;
          a.K = S_; a.lda = S_; a.ldb = S_; a.ldc = H_ * D_;
          a.zbase = g0; a.NG = GH; a.PBG = NB * GH;
          a.sAz = (long)eSS; a.sBz = DS;
          a.sCb = (long)S_ * H_ * D_; a.sCg = D_;
          gemm_nt<bf16, 0, false, false><<<dim3(4, 16, GS), 256, 16384, stream>>>(a);
        }
      }
    }
    {  // out[b0+b] = catb[b]·WoT^T + bo -> fp32
      GemmArgs a{};
      a.A = catb; a.Bm = wohi;
      a.C = out + (long)b0 * SD; a.bias = bo;
      a.K = H_ * D_; a.lda = H_ * D_; a.ldb = H_ * D_; a.ldc = D_;
      a.zbase = 0; a.NG = 1; a.PBG = NB;
      a.sAb = (long)S_ * H_ * D_;
      a.sCb = SD;
      gemm_nt<float, 1, false, false><<<dim3(4, 16, NB), 256, 16384, stream>>>(a);
    }
  }
}

// Round 9
// 1537.382 us; speedup vs baseline: 1.0476x; 1.0476x over previous
//
#include <hip/hip_runtime.h>

typedef __bf16 bf16;
typedef __bf16 bf16x8 __attribute__((ext_vector_type(8)));
typedef float f32x4 __attribute__((ext_vector_type(4)));

#define B_ 2
#define S_ 2048
#define D_ 512
#define H_ 8

__device__ inline void async_ld16(const void* g, void* l) {
  __builtin_amdgcn_global_load_lds((__attribute__((address_space(1))) void*)(g),
                                   (__attribute__((address_space(3))) void*)(l),
                                   16, 0, 0);
}

// fp32 -> bf16 hi + bf16 lo residual (split precision)
__global__ __launch_bounds__(256) void split_f32(const float* __restrict__ src,
                                                 bf16* __restrict__ hi, bf16* __restrict__ lo,
                                                 long n) {
  long i = (long)blockIdx.x * 256 + threadIdx.x;
  if (i >= n) return;
  float v = src[i];
  bf16 h = (bf16)v;
  hi[i] = h;
  lo[i] = (bf16)(v - (float)h);
}

// [z][R][C] fp32 -> [z][C][R] bf16 hi (+ optional lo residual plane)
__global__ __launch_bounds__(256) void transpose_f32(const float* __restrict__ src,
                                                     bf16* __restrict__ hi, bf16* __restrict__ lo,
                                                     int R, int C) {
  __shared__ float t[32][33];
  size_t zoff = (size_t)blockIdx.z * R * C;
  const float* s = src + zoff;
  int tx = threadIdx.x;  // 0..31
  int ty = threadIdx.y;  // 0..7
  int c0 = blockIdx.x * 32, r0 = blockIdx.y * 32;
#pragma unroll
  for (int i = 0; i < 4; ++i)
    t[ty + i * 8][tx] = s[(size_t)(r0 + ty + i * 8) * C + c0 + tx];
  __syncthreads();
#pragma unroll
  for (int i = 0; i < 4; ++i) {
    float v = t[tx][ty + i * 8];
    size_t o = zoff + (size_t)(c0 + ty + i * 8) * R + r0 + tx;
    bf16 h = (bf16)v;
    hi[o] = h;
    if (lo) lo[o] = (bf16)(v - (float)h);
  }
}

// out[b][s][e] = bo[e] prefill (split-K GEMM accumulates atomically on top)
__global__ __launch_bounds__(256) void prefill_bias(float* __restrict__ out,
                                                    const float* __restrict__ bo, long n) {
  long i = (long)blockIdx.x * 256 + threadIdx.x;
  if (i >= n) return;
  out[i] = bo[i & (D_ - 1)];
}

// Generalized batched GEMM args. blockIdx.z -> zi = zbase+z; decode
// p = zi/PBG, b = (zi%PBG)/NG, g = zi%NG; operand offset = p*sXp+b*sXb+g*sXg+z*sXz.
struct GemmArgs {
  const bf16 *A, *Alo, *Bm, *Blo;
  void* C; bf16* Clo;
  const float* bias;
  int K, lda, ldb, ldc;
  int zbase, NG, PBG;
  long sAp, sAb, sAg, sAz;
  long sBp, sBb, sBg, sBz;
  long sCp, sCb, sCg, sCz;
  long sbp, sbb, sbg, sbz;
};

// NT GEMM: C[m][n] = sum_k A[m][k]*B[n][k]. BIAS: 0=none,1=bias[n],2=bias[m].
// SIN: A,B have lo residual planes -> 3-term split MFMA (near-fp32 product).
// SOUT: emit bf16 hi + bf16 residual planes. ATOMIC: atomicAdd fp32 (split-K).
// Staging: global_load_lds width=16 (m97 recipe); XOR swizzle applied on the
// GLOBAL source address (LDS dest must be wave-linear base+lane*16), so the
// LDS image and fragment reads are byte-identical to the round-7/8 core.
template <typename OutT, int BIAS, bool SIN, bool SOUT, bool ATOMIC>
__global__ __launch_bounds__(256) void gemm_nt(GemmArgs p) {
  int zloc = blockIdx.z;
  int zi = p.zbase + zloc;
  int pp = zi / p.PBG; int rz = zi - pp * p.PBG;
  int bb = rz / p.NG;  int g = rz - bb * p.NG;
  long offA = pp * p.sAp + bb * p.sAb + g * p.sAg + (long)zloc * p.sAz;
  long offB = pp * p.sBp + bb * p.sBb + g * p.sBg + (long)zloc * p.sBz;
  long offC = pp * p.sCp + bb * p.sCb + g * p.sCg + (long)zloc * p.sCz;
  const bf16* A  = p.A + offA;
  const bf16* Bm = p.Bm + offB;
  const bf16* Al = SIN ? (p.Alo + offA) : nullptr;
  const bf16* Bl = SIN ? (p.Blo + offB) : nullptr;
  OutT* C = (OutT*)p.C + offC;
  bf16* Cl = SOUT ? (p.Clo + offC) : nullptr;
  const float* bias = nullptr;
  if (BIAS) bias = p.bias + (pp * p.sbp + bb * p.sbb + g * p.sbg + (long)zloc * p.sbz);

  __shared__ bf16 lA[4096];
  __shared__ bf16 lB[4096];
  __shared__ bf16 lAl[SIN ? 4096 : 1];
  __shared__ bf16 lBl[SIN ? 4096 : 1];

  int tid = threadIdx.x;
  int lane = tid & 63;
  int w = tid >> 6;
  int wm = (w >> 1) << 6;   // wave's 64-row origin in 128-tile
  int wn = (w & 1) << 6;    // wave's 64-col origin
  long bm = (long)blockIdx.y * 128;
  long bn = (long)blockIdx.x * 128;

  f32x4 acc[4][4] = {};
  int qd = lane >> 4;   // k-chunk selector
  int fr = lane & 15;   // row (A) / col (B) within 16-tile

  // LDS chunk q (= tid, tid+256) holds global (row r=q>>2, kchunk c=(q&3)^(r&3))
  int q0 = tid, q1 = tid + 256;
  int r0s = q0 >> 2, c0s = (q0 & 3) ^ (r0s & 3);
  int r1s = q1 >> 2, c1s = (q1 & 3) ^ (r1s & 3);

  for (int k0 = 0; k0 < p.K; k0 += 32) {
    long oa0 = (bm + r0s) * (long)p.lda + (k0 + c0s * 8);
    long oa1 = (bm + r1s) * (long)p.lda + (k0 + c1s * 8);
    long ob0 = (bn + r0s) * (long)p.ldb + (k0 + c0s * 8);
    long ob1 = (bn + r1s) * (long)p.ldb + (k0 + c1s * 8);
    __syncthreads();  // previous iteration's fragment reads complete
    async_ld16(A + oa0,  lA + (size_t)q0 * 8);
    async_ld16(A + oa1,  lA + (size_t)q1 * 8);
    async_ld16(Bm + ob0, lB + (size_t)q0 * 8);
    async_ld16(Bm + ob1, lB + (size_t)q1 * 8);
    if (SIN) {
      async_ld16(Al + oa0, lAl + (size_t)q0 * 8);
      async_ld16(Al + oa1, lAl + (size_t)q1 * 8);
      async_ld16(Bl + ob0, lBl + (size_t)q0 * 8);
      async_ld16(Bl + ob1, lBl + (size_t)q1 * 8);
    }
    __syncthreads();  // vmcnt(0) drain + barrier

    bf16x8 ah[4], bh[4], alv[4], blv[4];
#pragma unroll
    for (int i = 0; i < 4; ++i) {
      int m = wm + i * 16 + fr;
      size_t ia = ((size_t)m * 4 + (qd ^ (m & 3))) * 8;
      ah[i] = *(const bf16x8*)(lA + ia);
      if (SIN) alv[i] = *(const bf16x8*)(lAl + ia);
      int n = wn + i * 16 + fr;
      size_t ib = ((size_t)n * 4 + (qd ^ (n & 3))) * 8;
      bh[i] = *(const bf16x8*)(lB + ib);
      if (SIN) blv[i] = *(const bf16x8*)(lBl + ib);
    }
#pragma unroll
    for (int i = 0; i < 4; ++i)
#pragma unroll
      for (int j = 0; j < 4; ++j) {
        if (SIN) {
          acc[i][j] = __builtin_amdgcn_mfma_f32_16x16x32_bf16(alv[i], bh[j], acc[i][j], 0, 0, 0);
          acc[i][j] = __builtin_amdgcn_mfma_f32_16x16x32_bf16(ah[i], blv[j], acc[i][j], 0, 0, 0);
        }
        acc[i][j] = __builtin_amdgcn_mfma_f32_16x16x32_bf16(ah[i], bh[j], acc[i][j], 0, 0, 0);
      }
  }

  int rr0 = (lane >> 4) * 4;
#pragma unroll
  for (int i = 0; i < 4; ++i) {
#pragma unroll
    for (int j = 0; j < 4; ++j) {
#pragma unroll
      for (int r = 0; r < 4; ++r) {
        long row = bm + wm + i * 16 + rr0 + r;
        long col = bn + wn + j * 16 + fr;
        float v = acc[i][j][r];
        if (BIAS == 1) v += bias[col];
        if (BIAS == 2) v += bias[row];
        long idx = row * (long)p.ldc + col;
        if (ATOMIC) {
          atomicAdd((float*)C + idx, v);
        } else if (SOUT) {
          bf16 h = (bf16)v;
          ((bf16*)C)[idx] = h;
          Cl[idx] = (bf16)(v - (float)h);
        } else {
          C[idx] = (OutT)v;
        }
      }
    }
  }
}

// one block per row of 2048 fp32 scores -> bf16 probabilities
__global__ __launch_bounds__(256) void softmax_kernel(const float* __restrict__ src,
                                                      bf16* __restrict__ dst, int n) {
  size_t row = blockIdx.x;
  const float* s = src + row * (size_t)n;
  bf16* d = dst + row * (size_t)n;
  int t = threadIdx.x;
  float4 v0 = ((const float4*)s)[t * 2];
  float4 v1 = ((const float4*)s)[t * 2 + 1];
  float e[8] = {v0.x, v0.y, v0.z, v0.w, v1.x, v1.y, v1.z, v1.w};
  float m = e[0];
#pragma unroll
  for (int i = 1; i < 8; ++i) m = fmaxf(m, e[i]);
#pragma unroll
  for (int off = 32; off >= 1; off >>= 1) m = fmaxf(m, __shfl_xor(m, off, 64));
  __shared__ float smm[4];
  __shared__ float ss[4];
  int w = t >> 6;
  if ((t & 63) == 0) smm[w] = m;
  __syncthreads();
  m = fmaxf(fmaxf(smm[0], smm[1]), fmaxf(smm[2], smm[3]));
  float sum = 0.f;
#pragma unroll
  for (int i = 0; i < 8; ++i) { e[i] = __expf(e[i] - m); sum += e[i]; }
#pragma unroll
  for (int off = 32; off >= 1; off >>= 1) sum += __shfl_xor(sum, off, 64);
  if ((t & 63) == 0) ss[w] = sum;
  __syncthreads();
  sum = ss[0] + ss[1] + ss[2] + ss[3];
  float inv = 1.0f / sum;
  bf16x8 ov;
#pragma unroll
  for (int i = 0; i < 8; ++i) ov[i] = (bf16)(e[i] * inv);
  *(bf16x8*)(d + t * 8) = ov;
}

extern "C" void kernel_launch(void* const* d_in, const int* in_sizes, int n_in,
                              void* d_out, int out_size, void* d_ws, size_t ws_size,
                              hipStream_t stream) {
  const float* x  = (const float*)d_in[0];
  const float* Wq = (const float*)d_in[1];
  const float* bq = (const float*)d_in[2];
  const float* Wk = (const float*)d_in[3];
  const float* bk = (const float*)d_in[4];
  const float* Wv = (const float*)d_in[5];
  const float* bv = (const float*)d_in[6];
  const float* Wo = (const float*)d_in[7];
  const float* bo = (const float*)d_in[8];
  float* out = (float*)d_out;  // fp32 output (reference dtype)

  auto al = [](size_t v) { return (v + 255) & ~(size_t)255; };
  const size_t eX = (size_t)B_ * S_ * D_;
  const size_t eW = (size_t)H_ * D_ * D_;
  const size_t eSS = (size_t)S_ * S_;
  const long SD = (long)S_ * D_;
  const long DD = (long)D_ * D_;
  const long DS = (long)D_ * S_;

  size_t fixed = 2 * al(eX * 2) + 2 * al(2 * eW * 2) + al(eW * 2) + al(eW * 2)
               + al(2ULL * H_ * D_ * 4);
  int NB = 1, GH = 1, GS = 1; bool found = false;
  for (int nb = 2; nb >= 1 && !found; --nb)
    for (int gh = 8; gh >= 1 && !found; gh >>= 1)
      for (int gs = nb * gh; gs >= 1 && !found; gs >>= 1) {
        size_t need = fixed + al((size_t)nb * S_ * H_ * D_ * 2)
                    + 2 * al(2ULL * nb * gh * S_ * D_ * 2)
                    + al((size_t)nb * gh * D_ * S_ * 2)
                    + al((size_t)gs * eSS * 4) + al((size_t)gs * eSS * 2);
        if (need <= ws_size) { NB = nb; GH = gh; GS = gs; found = true; }
      }

  char* p0 = (char*)d_ws;
  size_t off = 0;
  bf16* xhi   = (bf16*)(p0 + off); off += al(eX * 2);
  bf16* xlo   = (bf16*)(p0 + off); off += al(eX * 2);
  bf16* wqkhi = (bf16*)(p0 + off); off += al(2 * eW * 2);   // [2H][e][d]
  bf16* wqklo = (bf16*)(p0 + off); off += al(2 * eW * 2);
  bf16* wvhi  = (bf16*)(p0 + off); off += al(eW * 2);       // [h][e][d]
  bf16* wohi  = (bf16*)(p0 + off); off += al(eW * 2);       // [e][h*D+d]
  float* bqk  = (float*)(p0 + off); off += al(2ULL * H_ * D_ * 4);
  bf16* catb  = (bf16*)(p0 + off); off += al((size_t)NB * S_ * H_ * D_ * 2);
  bf16* qkhi  = (bf16*)(p0 + off); off += al(2ULL * NB * GH * S_ * D_ * 2);  // [p][b][g][s][e]
  bf16* qklo  = (bf16*)(p0 + off); off += al(2ULL * NB * GH * S_ * D_ * 2);
  bf16* vT    = (bf16*)(p0 + off); off += al((size_t)NB * GH * D_ * S_ * 2); // [b][g][e][t]
  float* scores = (float*)(p0 + off); off += al((size_t)GS * eSS * 4);
  bf16* P     = (bf16*)(p0 + off);

  // ---- prep ----
  split_f32<<<dim3((unsigned)((eX + 255) / 256)), 256, 0, stream>>>(x, xhi, xlo, (long)eX);
  dim3 tb(32, 8, 1);
  transpose_f32<<<dim3(16, 16, H_), tb, 0, stream>>>(Wq, wqkhi, wqklo, D_, D_);
  transpose_f32<<<dim3(16, 16, H_), tb, 0, stream>>>(Wk, wqkhi + eW, wqklo + eW, D_, D_);
  transpose_f32<<<dim3(16, 16, H_), tb, 0, stream>>>(Wv, wvhi, nullptr, D_, D_);
  transpose_f32<<<dim3(16, 128, 1), tb, 0, stream>>>(Wo, wohi, nullptr, H_ * D_, D_);
  hipMemcpyAsync(bqk, bq, (size_t)H_ * D_ * 4, hipMemcpyDeviceToDevice, stream);
  hipMemcpyAsync(bqk + H_ * D_, bk, (size_t)H_ * D_ * 4, hipMemcpyDeviceToDevice, stream);
  prefill_bias<<<dim3((unsigned)((eX + 255) / 256)), 256, 0, stream>>>(out, bo, (long)eX);

  for (int b0 = 0; b0 < B_; b0 += NB) {
    for (int h0 = 0; h0 < H_; h0 += GH) {
      {  // Q+K projections, one dispatch: z=(p,b,g), split-in split-out
        GemmArgs a{};
        a.A = xhi + (long)b0 * SD; a.Alo = xlo + (long)b0 * SD;
        a.Bm = wqkhi + (long)h0 * DD; a.Blo = wqklo + (long)h0 * DD;
        a.C = qkhi; a.Clo = qklo; a.bias = bqk + (long)h0 * D_;
        a.K = D_; a.lda = D_; a.ldb = D_; a.ldc = D_;
        a.zbase = 0; a.NG = GH; a.PBG = NB * GH;
        a.sAb = SD;
        a.sBp = (long)H_ * DD; a.sBg = DD;
        a.sCz = SD;
        a.sbp = (long)H_ * D_; a.sbg = D_;
        gemm_nt<bf16, 1, true, true, false><<<dim3(4, 16, 2 * NB * GH), 256, 0, stream>>>(a);
      }
      {  // V^T: vT[b][g][e][t] = WvT[h]·x^T + bv (plain bf16)
        GemmArgs a{};
        a.A = wvhi + (long)h0 * DD; a.Bm = xhi + (long)b0 * SD;
        a.C = vT; a.bias = bv + (long)h0 * D_;
        a.K = D_; a.lda = D_; a.ldb = D_; a.ldc = S_;
        a.zbase = 0; a.NG = GH; a.PBG = NB * GH;
        a.sAg = DD;
        a.sBb = SD;
        a.sCz = DS;
        a.sbg = D_;
        gemm_nt<bf16, 2, false, false, false><<<dim3(16, 4, NB * GH), 256, 0, stream>>>(a);
      }
      for (int g0 = 0; g0 < NB * GH; g0 += GS) {
        {  // scores = Q·K^T (split-in, fp32 out)
          GemmArgs a{};
          a.A = qkhi + (long)g0 * SD;  a.Alo = qklo + (long)g0 * SD;
          a.Bm = qkhi + ((long)NB * GH + g0) * SD;
          a.Blo = qklo + ((long)NB * GH + g0) * SD;
          a.C = scores;
          a.K = D_; a.lda = D_; a.ldb = D_; a.ldc = S_;
          a.zbase = g0; a.NG = GH; a.PBG = NB * GH;
          a.sAz = SD; a.sBz = SD; a.sCz = (long)eSS;
          gemm_nt<float, 0, true, false, false><<<dim3(16, 16, GS), 256, 0, stream>>>(a);
        }
        softmax_kernel<<<dim3(GS * S_), 256, 0, stream>>>(scores, P, S_);
        {  // catb[b][s][(h0+g)*D+e] = P·vT^T
          GemmArgs a{};
          a.A = P; a.Bm = vT + (long)g0 * DS;
          a.C = catb + (long)h0 * D_;
          a.K = S_; a.lda = S_; a.ldb = S_; a.ldc = H_ * D_;
          a.zbase = g0; a.NG = GH; a.PBG = NB * GH;
          a.sAz = (long)eSS; a.sBz = DS;
          a.sCb = (long)S_ * H_ * D_; a.sCg = D_;
          gemm_nt<bf16, 0, false, false, false><<<dim3(4, 16, GS), 256, 0, stream>>>(a);
        }
      }
    }
    {  // out[b0+b] += catb[b]·WoT^T  (split-K over 4 chunks of 1024, atomic)
      GemmArgs a{};
      a.A = catb; a.Bm = wohi;
      a.C = out + (long)b0 * SD;
      a.K = 1024; a.lda = H_ * D_; a.ldb = H_ * D_; a.ldc = D_;
      a.zbase = 0; a.NG = 4; a.PBG = NB * 4;  // z=(b,kchunk)
      a.sAb = (long)S_ * H_ * D_; a.sAg = 1024;
      a.sBg = 1024;
      a.sCb = SD;
      gemm_nt<float, 0, false, false, true><<<dim3(4, 16, NB * 4), 256, 0, stream>>>(a);
    }
  }
}

// Round 10
// 1006.006 us; speedup vs baseline: 1.6009x; 1.5282x over previous
//
#include <hip/hip_runtime.h>

typedef __bf16 bf16;
typedef __bf16 bf16x8 __attribute__((ext_vector_type(8)));
typedef float f32x4 __attribute__((ext_vector_type(4)));

#define B_ 2
#define S_ 2048
#define D_ 512
#define H_ 8

__device__ inline void async_ld16(const void* g, void* l) {
  __builtin_amdgcn_global_load_lds((__attribute__((address_space(1))) void*)(g),
                                   (__attribute__((address_space(3))) void*)(l),
                                   16, 0, 0);
}

// fp32 -> bf16 hi + bf16 lo residual (split precision)
__global__ __launch_bounds__(256) void split_f32(const float* __restrict__ src,
                                                 bf16* __restrict__ hi, bf16* __restrict__ lo,
                                                 long n) {
  long i = (long)blockIdx.x * 256 + threadIdx.x;
  if (i >= n) return;
  float v = src[i];
  bf16 h = (bf16)v;
  hi[i] = h;
  lo[i] = (bf16)(v - (float)h);
}

// [z][R][C] fp32 -> [z][C][R] bf16 hi (+ optional lo residual plane)
__global__ __launch_bounds__(256) void transpose_f32(const float* __restrict__ src,
                                                     bf16* __restrict__ hi, bf16* __restrict__ lo,
                                                     int R, int C) {
  __shared__ float t[32][33];
  size_t zoff = (size_t)blockIdx.z * R * C;
  const float* s = src + zoff;
  int tx = threadIdx.x;  // 0..31
  int ty = threadIdx.y;  // 0..7
  int c0 = blockIdx.x * 32, r0 = blockIdx.y * 32;
#pragma unroll
  for (int i = 0; i < 4; ++i)
    t[ty + i * 8][tx] = s[(size_t)(r0 + ty + i * 8) * C + c0 + tx];
  __syncthreads();
#pragma unroll
  for (int i = 0; i < 4; ++i) {
    float v = t[tx][ty + i * 8];
    size_t o = zoff + (size_t)(c0 + ty + i * 8) * R + r0 + tx;
    bf16 h = (bf16)v;
    hi[o] = h;
    if (lo) lo[o] = (bf16)(v - (float)h);
  }
}

// out[i] = bo[i%D] + sum over nslab split-K partial slabs (deterministic)
__global__ __launch_bounds__(256) void reduce_out(const float* __restrict__ part,
                                                  const float* __restrict__ bo,
                                                  float* __restrict__ out, long n, int nslab) {
  long i = (long)blockIdx.x * 256 + threadIdx.x;
  if (i >= n) return;
  float v = bo[i & (D_ - 1)];
  for (int s = 0; s < nslab; ++s) v += part[(long)s * n + i];
  out[i] = v;
}

// Generalized batched GEMM args. blockIdx.z -> zi = zbase+z; decode
// p = zi/PBG, b = (zi%PBG)/NG, g = zi%NG; operand offset = p*sXp+b*sXb+g*sXg+z*sXz.
struct GemmArgs {
  const bf16 *A, *Alo, *Bm, *Blo;
  void* C; bf16* Clo;
  const float* bias;
  int K, lda, ldb, ldc;
  int zbase, NG, PBG;
  long sAp, sAb, sAg, sAz;
  long sBp, sBb, sBg, sBz;
  long sCp, sCb, sCg, sCz;
  long sbp, sbb, sbg, sbz;
};

// NT GEMM: C[m][n] = sum_k A[m][k]*B[n][k]. BIAS: 0=none,1=bias[n],2=bias[m].
// SIN: 3-term split MFMA (near-fp32). SOUT: bf16 hi + residual planes.
// Swizzle s(r)=(r>>1)&3 (period 8): fragment ds_read_b128 lands exactly 2
// lanes per 4-bank group (2-way = free, m136) — the round-8/9 s(r)=r&3 gave
// 4-way (lanes fr,fr+4,fr+8,fr+12 aliased) = 1.58x on the LDS critical path.
template <typename OutT, int BIAS, bool SIN, bool SOUT>
__global__ __launch_bounds__(256) void gemm_nt(GemmArgs p) {
  int zloc = blockIdx.z;
  int zi = p.zbase + zloc;
  int pp = zi / p.PBG; int rz = zi - pp * p.PBG;
  int bb = rz / p.NG;  int g = rz - bb * p.NG;
  long offA = pp * p.sAp + bb * p.sAb + g * p.sAg + (long)zloc * p.sAz;
  long offB = pp * p.sBp + bb * p.sBb + g * p.sBg + (long)zloc * p.sBz;
  long offC = pp * p.sCp + bb * p.sCb + g * p.sCg + (long)zloc * p.sCz;
  const bf16* A  = p.A + offA;
  const bf16* Bm = p.Bm + offB;
  const bf16* Al = SIN ? (p.Alo + offA) : nullptr;
  const bf16* Bl = SIN ? (p.Blo + offB) : nullptr;
  OutT* C = (OutT*)p.C + offC;
  bf16* Cl = SOUT ? (p.Clo + offC) : nullptr;
  const float* bias = nullptr;
  if (BIAS) bias = p.bias + (pp * p.sbp + bb * p.sbb + g * p.sbg + (long)zloc * p.sbz);

  __shared__ bf16 lA[4096];
  __shared__ bf16 lB[4096];
  __shared__ bf16 lAl[SIN ? 4096 : 1];
  __shared__ bf16 lBl[SIN ? 4096 : 1];

  int tid = threadIdx.x;
  int lane = tid & 63;
  int w = tid >> 6;
  int wm = (w >> 1) << 6;   // wave's 64-row origin in 128-tile
  int wn = (w & 1) << 6;    // wave's 64-col origin
  long bm = (long)blockIdx.y * 128;
  long bn = (long)blockIdx.x * 128;

  f32x4 acc[4][4] = {};
  int qd = lane >> 4;   // k-chunk selector
  int fr = lane & 15;   // row (A) / col (B) within 16-tile

  // LDS chunk q holds global (row r=q>>2, kchunk c=(q&3)^((r>>1)&3))
  int q0 = tid, q1 = tid + 256;
  int r0s = q0 >> 2, c0s = (q0 & 3) ^ ((r0s >> 1) & 3);
  int r1s = q1 >> 2, c1s = (q1 & 3) ^ ((r1s >> 1) & 3);

  for (int k0 = 0; k0 < p.K; k0 += 32) {
    long oa0 = (bm + r0s) * (long)p.lda + (k0 + c0s * 8);
    long oa1 = (bm + r1s) * (long)p.lda + (k0 + c1s * 8);
    long ob0 = (bn + r0s) * (long)p.ldb + (k0 + c0s * 8);
    long ob1 = (bn + r1s) * (long)p.ldb + (k0 + c1s * 8);
    __syncthreads();  // previous iteration's fragment reads complete
    async_ld16(A + oa0,  lA + (size_t)q0 * 8);
    async_ld16(A + oa1,  lA + (size_t)q1 * 8);
    async_ld16(Bm + ob0, lB + (size_t)q0 * 8);
    async_ld16(Bm + ob1, lB + (size_t)q1 * 8);
    if (SIN) {
      async_ld16(Al + oa0, lAl + (size_t)q0 * 8);
      async_ld16(Al + oa1, lAl + (size_t)q1 * 8);
      async_ld16(Bl + ob0, lBl + (size_t)q0 * 8);
      async_ld16(Bl + ob1, lBl + (size_t)q1 * 8);
    }
    __syncthreads();  // vmcnt(0) drain + barrier

    bf16x8 ah[4], bh[4], alv[4], blv[4];
#pragma unroll
    for (int i = 0; i < 4; ++i) {
      int m = wm + i * 16 + fr;
      size_t ia = ((size_t)m * 4 + (qd ^ ((m >> 1) & 3))) * 8;
      ah[i] = *(const bf16x8*)(lA + ia);
      if (SIN) alv[i] = *(const bf16x8*)(lAl + ia);
      int n = wn + i * 16 + fr;
      size_t ib = ((size_t)n * 4 + (qd ^ ((n >> 1) & 3))) * 8;
      bh[i] = *(const bf16x8*)(lB + ib);
      if (SIN) blv[i] = *(const bf16x8*)(lBl + ib);
    }
#pragma unroll
    for (int i = 0; i < 4; ++i)
#pragma unroll
      for (int j = 0; j < 4; ++j) {
        if (SIN) {
          acc[i][j] = __builtin_amdgcn_mfma_f32_16x16x32_bf16(alv[i], bh[j], acc[i][j], 0, 0, 0);
          acc[i][j] = __builtin_amdgcn_mfma_f32_16x16x32_bf16(ah[i], blv[j], acc[i][j], 0, 0, 0);
        }
        acc[i][j] = __builtin_amdgcn_mfma_f32_16x16x32_bf16(ah[i], bh[j], acc[i][j], 0, 0, 0);
      }
  }

  int rr0 = (lane >> 4) * 4;
#pragma unroll
  for (int i = 0; i < 4; ++i) {
#pragma unroll
    for (int j = 0; j < 4; ++j) {
#pragma unroll
      for (int r = 0; r < 4; ++r) {
        long row = bm + wm + i * 16 + rr0 + r;
        long col = bn + wn + j * 16 + fr;
        float v = acc[i][j][r];
        if (BIAS == 1) v += bias[col];
        if (BIAS == 2) v += bias[row];
        long idx = row * (long)p.ldc + col;
        if (SOUT) {
          bf16 h = (bf16)v;
          ((bf16*)C)[idx] = h;
          Cl[idx] = (bf16)(v - (float)h);
        } else {
          C[idx] = (OutT)v;
        }
      }
    }
  }
}

// one block per row of 2048 fp32 scores -> bf16 probabilities
__global__ __launch_bounds__(256) void softmax_kernel(const float* __restrict__ src,
                                                      bf16* __restrict__ dst, int n) {
  size_t row = blockIdx.x;
  const float* s = src + row * (size_t)n;
  bf16* d = dst + row * (size_t)n;
  int t = threadIdx.x;
  float4 v0 = ((const float4*)s)[t * 2];
  float4 v1 = ((const float4*)s)[t * 2 + 1];
  float e[8] = {v0.x, v0.y, v0.z, v0.w, v1.x, v1.y, v1.z, v1.w};
  float m = e[0];
#pragma unroll
  for (int i = 1; i < 8; ++i) m = fmaxf(m, e[i]);
#pragma unroll
  for (int off = 32; off >= 1; off >>= 1) m = fmaxf(m, __shfl_xor(m, off, 64));
  __shared__ float smm[4];
  __shared__ float ss[4];
  int w = t >> 6;
  if ((t & 63) == 0) smm[w] = m;
  __syncthreads();
  m = fmaxf(fmaxf(smm[0], smm[1]), fmaxf(smm[2], smm[3]));
  float sum = 0.f;
#pragma unroll
  for (int i = 0; i < 8; ++i) { e[i] = __expf(e[i] - m); sum += e[i]; }
#pragma unroll
  for (int off = 32; off >= 1; off >>= 1) sum += __shfl_xor(sum, off, 64);
  if ((t & 63) == 0) ss[w] = sum;
  __syncthreads();
  sum = ss[0] + ss[1] + ss[2] + ss[3];
  float inv = 1.0f / sum;
  bf16x8 ov;
#pragma unroll
  for (int i = 0; i < 8; ++i) ov[i] = (bf16)(e[i] * inv);
  *(bf16x8*)(d + t * 8) = ov;
}

extern "C" void kernel_launch(void* const* d_in, const int* in_sizes, int n_in,
                              void* d_out, int out_size, void* d_ws, size_t ws_size,
                              hipStream_t stream) {
  const float* x  = (const float*)d_in[0];
  const float* Wq = (const float*)d_in[1];
  const float* bq = (const float*)d_in[2];
  const float* Wk = (const float*)d_in[3];
  const float* bk = (const float*)d_in[4];
  const float* Wv = (const float*)d_in[5];
  const float* bv = (const float*)d_in[6];
  const float* Wo = (const float*)d_in[7];
  const float* bo = (const float*)d_in[8];
  float* out = (float*)d_out;  // fp32 output (reference dtype)

  auto al = [](size_t v) { return (v + 255) & ~(size_t)255; };
  const size_t eX = (size_t)B_ * S_ * D_;
  const size_t eW = (size_t)H_ * D_ * D_;
  const size_t eSS = (size_t)S_ * S_;
  const long SD = (long)S_ * D_;
  const long DD = (long)D_ * D_;
  const long DS = (long)D_ * S_;

  size_t fixed = 2 * al(eX * 2) + 2 * al(2 * eW * 2) + al(eW * 2) + al(eW * 2)
               + al(2ULL * H_ * D_ * 4);
  int NB = 1, GH = 1, GS = 1; bool found = false;
  for (int nb = 2; nb >= 1 && !found; --nb)
    for (int gh = 8; gh >= 1 && !found; gh >>= 1)
      for (int gs = nb * gh; gs >= 1 && !found; gs >>= 1) {
        size_t need = fixed + al((size_t)nb * S_ * H_ * D_ * 2)
                    + 2 * al(2ULL * nb * gh * S_ * D_ * 2)
                    + al((size_t)nb * gh * D_ * S_ * 2)
                    + al(4ULL * nb * SD * 4)                 // out-proj partials
                    + al((size_t)gs * eSS * 4) + al((size_t)gs * eSS * 2);
        if (need <= ws_size) { NB = nb; GH = gh; GS = gs; found = true; }
      }

  char* p0 = (char*)d_ws;
  size_t off = 0;
  bf16* xhi   = (bf16*)(p0 + off); off += al(eX * 2);
  bf16* xlo   = (bf16*)(p0 + off); off += al(eX * 2);
  bf16* wqkhi = (bf16*)(p0 + off); off += al(2 * eW * 2);   // [2H][e][d]
  bf16* wqklo = (bf16*)(p0 + off); off += al(2 * eW * 2);
  bf16* wvhi  = (bf16*)(p0 + off); off += al(eW * 2);       // [h][e][d]
  bf16* wohi  = (bf16*)(p0 + off); off += al(eW * 2);       // [e][h*D+d]
  float* bqk  = (float*)(p0 + off); off += al(2ULL * H_ * D_ * 4);
  bf16* catb  = (bf16*)(p0 + off); off += al((size_t)NB * S_ * H_ * D_ * 2);
  bf16* qkhi  = (bf16*)(p0 + off); off += al(2ULL * NB * GH * S_ * D_ * 2);  // [p][b][g][s][e]
  bf16* qklo  = (bf16*)(p0 + off); off += al(2ULL * NB * GH * S_ * D_ * 2);
  bf16* vT    = (bf16*)(p0 + off); off += al((size_t)NB * GH * D_ * S_ * 2); // [b][g][e][t]
  float* opart = (float*)(p0 + off); off += al(4ULL * NB * SD * 4);          // [kc][b][s][e]
  float* scores = (float*)(p0 + off); off += al((size_t)GS * eSS * 4);
  bf16* P     = (bf16*)(p0 + off);

  // ---- prep ----
  split_f32<<<dim3((unsigned)((eX + 255) / 256)), 256, 0, stream>>>(x, xhi, xlo, (long)eX);
  dim3 tb(32, 8, 1);
  transpose_f32<<<dim3(16, 16, H_), tb, 0, stream>>>(Wq, wqkhi, wqklo, D_, D_);
  transpose_f32<<<dim3(16, 16, H_), tb, 0, stream>>>(Wk, wqkhi + eW, wqklo + eW, D_, D_);
  transpose_f32<<<dim3(16, 16, H_), tb, 0, stream>>>(Wv, wvhi, nullptr, D_, D_);
  transpose_f32<<<dim3(16, 128, 1), tb, 0, stream>>>(Wo, wohi, nullptr, H_ * D_, D_);
  hipMemcpyAsync(bqk, bq, (size_t)H_ * D_ * 4, hipMemcpyDeviceToDevice, stream);
  hipMemcpyAsync(bqk + H_ * D_, bk, (size_t)H_ * D_ * 4, hipMemcpyDeviceToDevice, stream);

  for (int b0 = 0; b0 < B_; b0 += NB) {
    for (int h0 = 0; h0 < H_; h0 += GH) {
      {  // Q+K projections, one dispatch: z=(p,b,g), split-in split-out
        GemmArgs a{};
        a.A = xhi + (long)b0 * SD; a.Alo = xlo + (long)b0 * SD;
        a.Bm = wqkhi + (long)h0 * DD; a.Blo = wqklo + (long)h0 * DD;
        a.C = qkhi; a.Clo = qklo; a.bias = bqk + (long)h0 * D_;
        a.K = D_; a.lda = D_; a.ldb = D_; a.ldc = D_;
        a.zbase = 0; a.NG = GH; a.PBG = NB * GH;
        a.sAb = SD;
        a.sBp = (long)H_ * DD; a.sBg = DD;
        a.sCz = SD;
        a.sbp = (long)H_ * D_; a.sbg = D_;
        gemm_nt<bf16, 1, true, true><<<dim3(4, 16, 2 * NB * GH), 256, 0, stream>>>(a);
      }
      {  // V^T: vT[b][g][e][t] = WvT[h]·x^T + bv (plain bf16)
        GemmArgs a{};
        a.A = wvhi + (long)h0 * DD; a.Bm = xhi + (long)b0 * SD;
        a.C = vT; a.bias = bv + (long)h0 * D_;
        a.K = D_; a.lda = D_; a.ldb = D_; a.ldc = S_;
        a.zbase = 0; a.NG = GH; a.PBG = NB * GH;
        a.sAg = DD;
        a.sBb = SD;
        a.sCz = DS;
        a.sbg = D_;
        gemm_nt<bf16, 2, false, false><<<dim3(16, 4, NB * GH), 256, 0, stream>>>(a);
      }
      for (int g0 = 0; g0 < NB * GH; g0 += GS) {
        {  // scores = Q·K^T (split-in, fp32 out)
          GemmArgs a{};
          a.A = qkhi + (long)g0 * SD;  a.Alo = qklo + (long)g0 * SD;
          a.Bm = qkhi + ((long)NB * GH + g0) * SD;
          a.Blo = qklo + ((long)NB * GH + g0) * SD;
          a.C = scores;
          a.K = D_; a.lda = D_; a.ldb = D_; a.ldc = S_;
          a.zbase = g0; a.NG = GH; a.PBG = NB * GH;
          a.sAz = SD; a.sBz = SD; a.sCz = (long)eSS;
          gemm_nt<float, 0, true, false><<<dim3(16, 16, GS), 256, 0, stream>>>(a);
        }
        softmax_kernel<<<dim3(GS * S_), 256, 0, stream>>>(scores, P, S_);
        {  // catb[b][s][(h0+g)*D+e] = P·vT^T
          GemmArgs a{};
          a.A = P; a.Bm = vT + (long)g0 * DS;
          a.C = catb + (long)h0 * D_;
          a.K = S_; a.lda = S_; a.ldb = S_; a.ldc = H_ * D_;
          a.zbase = g0; a.NG = GH; a.PBG = NB * GH;
          a.sAz = (long)eSS; a.sBz = DS;
          a.sCb = (long)S_ * H_ * D_; a.sCg = D_;
          gemm_nt<bf16, 0, false, false><<<dim3(4, 16, GS), 256, 0, stream>>>(a);
        }
      }
    }
    {  // opart[kc][b] = catb[b][:, kc-slab]·WoT[:, kc-slab]^T  (split-K, no atomics)
      GemmArgs a{};
      a.A = catb; a.Bm = wohi;
      a.C = opart;
      a.K = 1024; a.lda = H_ * D_; a.ldb = H_ * D_; a.ldc = D_;
      a.zbase = 0; a.NG = 4; a.PBG = NB * 4;  // z=(b,kchunk)
      a.sAb = (long)S_ * H_ * D_; a.sAg = 1024;
      a.sBg = 1024;
      a.sCb = SD; a.sCg = (long)NB * SD;
      gemm_nt<float, 0, false, false><<<dim3(4, 16, NB * 4), 256, 0, stream>>>(a);
    }
    reduce_out<<<dim3((unsigned)(((long)NB * SD + 255) / 256)), 256, 0, stream>>>(
        opart, bo, out + (long)b0 * SD, (long)NB * SD, 4);
  }
}

// Round 11
// 849.238 us; speedup vs baseline: 1.8965x; 1.1846x over previous
//
#include <hip/hip_runtime.h>

typedef _Float16 f16;
typedef _Float16 f16x8 __attribute__((ext_vector_type(8)));
typedef float f32x4 __attribute__((ext_vector_type(4)));

#define B_ 2
#define S_ 2048
#define D_ 512
#define H_ 8

__device__ inline void async_ld16(const void* g, void* l) {
  __builtin_amdgcn_global_load_lds((__attribute__((address_space(1))) void*)(g),
                                   (__attribute__((address_space(3))) void*)(l),
                                   16, 0, 0);
}

// fp32 -> fp16
__global__ __launch_bounds__(256) void cvt_f16(const float* __restrict__ src,
                                               f16* __restrict__ dst, long n) {
  long i = (long)blockIdx.x * 256 + threadIdx.x;
  if (i >= n) return;
  dst[i] = (f16)src[i];
}

// [z][R][C] fp32 -> [z][C][R] fp16
__global__ __launch_bounds__(256) void transpose_f32(const float* __restrict__ src,
                                                     f16* __restrict__ dst, int R, int C) {
  __shared__ float t[32][33];
  size_t zoff = (size_t)blockIdx.z * R * C;
  const float* s = src + zoff;
  int tx = threadIdx.x;  // 0..31
  int ty = threadIdx.y;  // 0..7
  int c0 = blockIdx.x * 32, r0 = blockIdx.y * 32;
#pragma unroll
  for (int i = 0; i < 4; ++i)
    t[ty + i * 8][tx] = s[(size_t)(r0 + ty + i * 8) * C + c0 + tx];
  __syncthreads();
#pragma unroll
  for (int i = 0; i < 4; ++i)
    dst[zoff + (size_t)(c0 + ty + i * 8) * R + r0 + tx] = (f16)t[tx][ty + i * 8];
}

// out[i] = bo[i%D] + sum over nslab split-K partial slabs (deterministic)
__global__ __launch_bounds__(256) void reduce_out(const float* __restrict__ part,
                                                  const float* __restrict__ bo,
                                                  float* __restrict__ out, long n, int nslab) {
  long i = (long)blockIdx.x * 256 + threadIdx.x;
  if (i >= n) return;
  float v = bo[i & (D_ - 1)];
  for (int s = 0; s < nslab; ++s) v += part[(long)s * n + i];
  out[i] = v;
}

// Generalized batched GEMM args. blockIdx.z -> zi = zbase+z; decode
// p = zi/PBG, b = (zi%PBG)/NG, g = zi%NG; operand offset = p*sXp+b*sXb+g*sXg+z*sXz.
struct GemmArgs {
  const f16 *A, *Bm;
  void* C;
  const float* bias;
  int K, lda, ldb, ldc;
  int zbase, NG, PBG;
  long sAp, sAb, sAg, sAz;
  long sBp, sBb, sBg, sBz;
  long sCp, sCb, sCg, sCz;
  long sbp, sbb, sbg, sbz;
};

// NT GEMM fp16: C[m][n] = sum_k A[m][k]*B[n][k], fp32 accumulate.
// BIAS: 0=none,1=bias[n],2=bias[m]. Swizzle s(r)=(r>>1)&3 (period 8):
// fragment ds_read_b128 = 2 lanes per 4-bank group (2-way = free, m136;
// verified round 10: SQ_LDS_BANK_CONFLICT 8.4M -> 0, 1537 -> 1006 us).
template <typename OutT, int BIAS>
__global__ __launch_bounds__(256) void gemm_nt(GemmArgs p) {
  int zloc = blockIdx.z;
  int zi = p.zbase + zloc;
  int pp = zi / p.PBG; int rz = zi - pp * p.PBG;
  int bb = rz / p.NG;  int g = rz - bb * p.NG;
  const f16* A  = p.A + (pp * p.sAp + bb * p.sAb + g * p.sAg + (long)zloc * p.sAz);
  const f16* Bm = p.Bm + (pp * p.sBp + bb * p.sBb + g * p.sBg + (long)zloc * p.sBz);
  OutT* C = (OutT*)p.C + (pp * p.sCp + bb * p.sCb + g * p.sCg + (long)zloc * p.sCz);
  const float* bias = nullptr;
  if (BIAS) bias = p.bias + (pp * p.sbp + bb * p.sbb + g * p.sbg + (long)zloc * p.sbz);

  __shared__ f16 lA[4096];
  __shared__ f16 lB[4096];

  int tid = threadIdx.x;
  int lane = tid & 63;
  int w = tid >> 6;
  int wm = (w >> 1) << 6;   // wave's 64-row origin in 128-tile
  int wn = (w & 1) << 6;    // wave's 64-col origin
  long bm = (long)blockIdx.y * 128;
  long bn = (long)blockIdx.x * 128;

  f32x4 acc[4][4] = {};
  int qd = lane >> 4;   // k-chunk selector
  int fr = lane & 15;   // row (A) / col (B) within 16-tile

  // LDS chunk q holds global (row r=q>>2, kchunk c=(q&3)^((r>>1)&3))
  int q0 = tid, q1 = tid + 256;
  int r0s = q0 >> 2, c0s = (q0 & 3) ^ ((r0s >> 1) & 3);
  int r1s = q1 >> 2, c1s = (q1 & 3) ^ ((r1s >> 1) & 3);

  for (int k0 = 0; k0 < p.K; k0 += 32) {
    long oa0 = (bm + r0s) * (long)p.lda + (k0 + c0s * 8);
    long oa1 = (bm + r1s) * (long)p.lda + (k0 + c1s * 8);
    long ob0 = (bn + r0s) * (long)p.ldb + (k0 + c0s * 8);
    long ob1 = (bn + r1s) * (long)p.ldb + (k0 + c1s * 8);
    __syncthreads();  // previous iteration's fragment reads complete
    async_ld16(A + oa0,  lA + (size_t)q0 * 8);
    async_ld16(A + oa1,  lA + (size_t)q1 * 8);
    async_ld16(Bm + ob0, lB + (size_t)q0 * 8);
    async_ld16(Bm + ob1, lB + (size_t)q1 * 8);
    __syncthreads();  // vmcnt(0) drain + barrier

    f16x8 ah[4], bh[4];
#pragma unroll
    for (int i = 0; i < 4; ++i) {
      int m = wm + i * 16 + fr;
      ah[i] = *(const f16x8*)(lA + ((size_t)m * 4 + (qd ^ ((m >> 1) & 3))) * 8);
      int n = wn + i * 16 + fr;
      bh[i] = *(const f16x8*)(lB + ((size_t)n * 4 + (qd ^ ((n >> 1) & 3))) * 8);
    }
#pragma unroll
    for (int i = 0; i < 4; ++i)
#pragma unroll
      for (int j = 0; j < 4; ++j)
        acc[i][j] = __builtin_amdgcn_mfma_f32_16x16x32_f16(ah[i], bh[j], acc[i][j], 0, 0, 0);
  }

  int rr0 = (lane >> 4) * 4;
#pragma unroll
  for (int i = 0; i < 4; ++i) {
#pragma unroll
    for (int j = 0; j < 4; ++j) {
#pragma unroll
      for (int r = 0; r < 4; ++r) {
        long row = bm + wm + i * 16 + rr0 + r;
        long col = bn + wn + j * 16 + fr;
        float v = acc[i][j][r];
        if (BIAS == 1) v += bias[col];
        if (BIAS == 2) v += bias[row];
        C[row * (long)p.ldc + col] = (OutT)v;
      }
    }
  }
}

// one block per row of 2048 fp32 scores -> fp16 probabilities
__global__ __launch_bounds__(256) void softmax_kernel(const float* __restrict__ src,
                                                      f16* __restrict__ dst, int n) {
  size_t row = blockIdx.x;
  const float* s = src + row * (size_t)n;
  f16* d = dst + row * (size_t)n;
  int t = threadIdx.x;
  float4 v0 = ((const float4*)s)[t * 2];
  float4 v1 = ((const float4*)s)[t * 2 + 1];
  float e[8] = {v0.x, v0.y, v0.z, v0.w, v1.x, v1.y, v1.z, v1.w};
  float m = e[0];
#pragma unroll
  for (int i = 1; i < 8; ++i) m = fmaxf(m, e[i]);
#pragma unroll
  for (int off = 32; off >= 1; off >>= 1) m = fmaxf(m, __shfl_xor(m, off, 64));
  __shared__ float smm[4];
  __shared__ float ss[4];
  int w = t >> 6;
  if ((t & 63) == 0) smm[w] = m;
  __syncthreads();
  m = fmaxf(fmaxf(smm[0], smm[1]), fmaxf(smm[2], smm[3]));
  float sum = 0.f;
#pragma unroll
  for (int i = 0; i < 8; ++i) { e[i] = __expf(e[i] - m); sum += e[i]; }
#pragma unroll
  for (int off = 32; off >= 1; off >>= 1) sum += __shfl_xor(sum, off, 64);
  if ((t & 63) == 0) ss[w] = sum;
  __syncthreads();
  sum = ss[0] + ss[1] + ss[2] + ss[3];
  float inv = 1.0f / sum;
  f16x8 ov;
#pragma unroll
  for (int i = 0; i < 8; ++i) ov[i] = (f16)(e[i] * inv);
  *(f16x8*)(d + t * 8) = ov;
}

extern "C" void kernel_launch(void* const* d_in, const int* in_sizes, int n_in,
                              void* d_out, int out_size, void* d_ws, size_t ws_size,
                              hipStream_t stream) {
  const float* x  = (const float*)d_in[0];
  const float* Wq = (const float*)d_in[1];
  const float* bq = (const float*)d_in[2];
  const float* Wk = (const float*)d_in[3];
  const float* bk = (const float*)d_in[4];
  const float* Wv = (const float*)d_in[5];
  const float* bv = (const float*)d_in[6];
  const float* Wo = (const float*)d_in[7];
  const float* bo = (const float*)d_in[8];
  float* out = (float*)d_out;  // fp32 output (reference dtype)

  auto al = [](size_t v) { return (v + 255) & ~(size_t)255; };
  const size_t eX = (size_t)B_ * S_ * D_;
  const size_t eW = (size_t)H_ * D_ * D_;
  const size_t eSS = (size_t)S_ * S_;
  const long SD = (long)S_ * D_;
  const long DD = (long)D_ * D_;
  const long DS = (long)D_ * S_;

  size_t fixed = al(eX * 2) + al(2 * eW * 2) + al(eW * 2) + al(eW * 2)
               + al(2ULL * H_ * D_ * 4);
  int NB = 1, GH = 1, GS = 1; bool found = false;
  for (int nb = 2; nb >= 1 && !found; --nb)
    for (int gh = 8; gh >= 1 && !found; gh >>= 1)
      for (int gs = nb * gh; gs >= 1 && !found; gs >>= 1) {
        size_t need = fixed + al((size_t)nb * S_ * H_ * D_ * 2)
                    + al(2ULL * nb * gh * S_ * D_ * 2)
                    + al((size_t)nb * gh * D_ * S_ * 2)
                    + al(4ULL * nb * SD * 4)
                    + al((size_t)gs * eSS * 4) + al((size_t)gs * eSS * 2);
        if (need <= ws_size) { NB = nb; GH = gh; GS = gs; found = true; }
      }

  char* p0 = (char*)d_ws;
  size_t off = 0;
  f16* xh    = (f16*)(p0 + off); off += al(eX * 2);
  f16* wqk   = (f16*)(p0 + off); off += al(2 * eW * 2);   // [2H][e][d]
  f16* wv    = (f16*)(p0 + off); off += al(eW * 2);       // [h][e][d]
  f16* wo    = (f16*)(p0 + off); off += al(eW * 2);       // [e][h*D+d]
  float* bqk = (float*)(p0 + off); off += al(2ULL * H_ * D_ * 4);
  f16* catb  = (f16*)(p0 + off); off += al((size_t)NB * S_ * H_ * D_ * 2);
  f16* qk    = (f16*)(p0 + off); off += al(2ULL * NB * GH * S_ * D_ * 2);  // [p][b][g][s][e]
  f16* vT    = (f16*)(p0 + off); off += al((size_t)NB * GH * D_ * S_ * 2); // [b][g][e][t]
  float* opart = (float*)(p0 + off); off += al(4ULL * NB * SD * 4);        // [kc][b][s][e]
  float* scores = (float*)(p0 + off); off += al((size_t)GS * eSS * 4);
  f16* P     = (f16*)(p0 + off);

  // ---- prep ----
  cvt_f16<<<dim3((unsigned)((eX + 255) / 256)), 256, 0, stream>>>(x, xh, (long)eX);
  dim3 tb(32, 8, 1);
  transpose_f32<<<dim3(16, 16, H_), tb, 0, stream>>>(Wq, wqk, D_, D_);
  transpose_f32<<<dim3(16, 16, H_), tb, 0, stream>>>(Wk, wqk + eW, D_, D_);
  transpose_f32<<<dim3(16, 16, H_), tb, 0, stream>>>(Wv, wv, D_, D_);
  transpose_f32<<<dim3(16, 128, 1), tb, 0, stream>>>(Wo, wo, H_ * D_, D_);
  hipMemcpyAsync(bqk, bq, (size_t)H_ * D_ * 4, hipMemcpyDeviceToDevice, stream);
  hipMemcpyAsync(bqk + H_ * D_, bk, (size_t)H_ * D_ * 4, hipMemcpyDeviceToDevice, stream);

  for (int b0 = 0; b0 < B_; b0 += NB) {
    for (int h0 = 0; h0 < H_; h0 += GH) {
      {  // Q+K projections, one dispatch: z=(p,b,g)
        GemmArgs a{};
        a.A = xh + (long)b0 * SD;
        a.Bm = wqk + (long)h0 * DD;
        a.C = qk; a.bias = bqk + (long)h0 * D_;
        a.K = D_; a.lda = D_; a.ldb = D_; a.ldc = D_;
        a.zbase = 0; a.NG = GH; a.PBG = NB * GH;
        a.sAb = SD;
        a.sBp = (long)H_ * DD; a.sBg = DD;
        a.sCz = SD;
        a.sbp = (long)H_ * D_; a.sbg = D_;
        gemm_nt<f16, 1><<<dim3(4, 16, 2 * NB * GH), 256, 0, stream>>>(a);
      }
      {  // V^T: vT[b][g][e][t] = WvT[h]·x^T + bv
        GemmArgs a{};
        a.A = wv + (long)h0 * DD; a.Bm = xh + (long)b0 * SD;
        a.C = vT; a.bias = bv + (long)h0 * D_;
        a.K = D_; a.lda = D_; a.ldb = D_; a.ldc = S_;
        a.zbase = 0; a.NG = GH; a.PBG = NB * GH;
        a.sAg = DD;
        a.sBb = SD;
        a.sCz = DS;
        a.sbg = D_;
        gemm_nt<f16, 2><<<dim3(16, 4, NB * GH), 256, 0, stream>>>(a);
      }
      for (int g0 = 0; g0 < NB * GH; g0 += GS) {
        {  // scores = Q·K^T (fp32 out)
          GemmArgs a{};
          a.A = qk + (long)g0 * SD;
          a.Bm = qk + ((long)NB * GH + g0) * SD;
          a.C = scores;
          a.K = D_; a.lda = D_; a.ldb = D_; a.ldc = S_;
          a.zbase = g0; a.NG = GH; a.PBG = NB * GH;
          a.sAz = SD; a.sBz = SD; a.sCz = (long)eSS;
          gemm_nt<float, 0><<<dim3(16, 16, GS), 256, 0, stream>>>(a);
        }
        softmax_kernel<<<dim3(GS * S_), 256, 0, stream>>>(scores, P, S_);
        {  // catb[b][s][(h0+g)*D+e] = P·vT^T
          GemmArgs a{};
          a.A = P; a.Bm = vT + (long)g0 * DS;
          a.C = catb + (long)h0 * D_;
          a.K = S_; a.lda = S_; a.ldb = S_; a.ldc = H_ * D_;
          a.zbase = g0; a.NG = GH; a.PBG = NB * GH;
          a.sAz = (long)eSS; a.sBz = DS;
          a.sCb = (long)S_ * H_ * D_; a.sCg = D_;
          gemm_nt<f16, 0><<<dim3(4, 16, GS), 256, 0, stream>>>(a);
        }
      }
    }
    {  // opart[kc][b] = catb[b][:, kc-slab]·WoT[:, kc-slab]^T  (split-K)
      GemmArgs a{};
      a.A = catb; a.Bm = wo;
      a.C = opart;
      a.K = 1024; a.lda = H_ * D_; a.ldb = H_ * D_; a.ldc = D_;
      a.zbase = 0; a.NG = 4; a.PBG = NB * 4;  // z=(b,kchunk)
      a.sAb = (long)S_ * H_ * D_; a.sAg = 1024;
      a.sBg = 1024;
      a.sCb = SD; a.sCg = (long)NB * SD;
      gemm_nt<float, 0><<<dim3(4, 16, NB * 4), 256, 0, stream>>>(a);
    }
    reduce_out<<<dim3((unsigned)(((long)NB * SD + 255) / 256)), 256, 0, stream>>>(
        opart, bo, out + (long)b0 * SD, (long)NB * SD, 4);
  }
}

// Round 12
// 718.362 us; speedup vs baseline: 2.2420x; 1.1822x over previous
//
#include <hip/hip_runtime.h>

typedef _Float16 f16;
typedef _Float16 f16x8 __attribute__((ext_vector_type(8)));
typedef float f32x4 __attribute__((ext_vector_type(4)));

#define B_ 2
#define S_ 2048
#define D_ 512
#define H_ 8

__device__ inline void async_ld16(const void* g, void* l) {
  __builtin_amdgcn_global_load_lds((__attribute__((address_space(1))) void*)(g),
                                   (__attribute__((address_space(3))) void*)(l),
                                   16, 0, 0);
}

// monotone uint mapping of fp32 for atomicMax-based row max
__device__ inline unsigned fmap(float f) {
  unsigned u = __float_as_uint(f);
  return (u & 0x80000000u) ? ~u : (u | 0x80000000u);
}
__device__ inline float funmap(unsigned k) {
  return (k & 0x80000000u) ? __uint_as_float(k ^ 0x80000000u) : __uint_as_float(~k);
}

// fp32 -> fp16
__global__ __launch_bounds__(256) void cvt_f16(const float* __restrict__ src,
                                               f16* __restrict__ dst, long n) {
  long i = (long)blockIdx.x * 256 + threadIdx.x;
  if (i >= n) return;
  dst[i] = (f16)src[i];
}

// [z][R][C] fp32 -> [z][C][R] fp16
__global__ __launch_bounds__(256) void transpose_f32(const float* __restrict__ src,
                                                     f16* __restrict__ dst, int R, int C) {
  __shared__ float t[32][33];
  size_t zoff = (size_t)blockIdx.z * R * C;
  const float* s = src + zoff;
  int tx = threadIdx.x;
  int ty = threadIdx.y;
  int c0 = blockIdx.x * 32, r0 = blockIdx.y * 32;
#pragma unroll
  for (int i = 0; i < 4; ++i)
    t[ty + i * 8][tx] = s[(size_t)(r0 + ty + i * 8) * C + c0 + tx];
  __syncthreads();
#pragma unroll
  for (int i = 0; i < 4; ++i)
    dst[zoff + (size_t)(c0 + ty + i * 8) * R + r0 + tx] = (f16)t[tx][ty + i * 8];
}

// out[i] = bo[i%D] + sum over nslab split-K partial slabs
__global__ __launch_bounds__(256) void reduce_out(const float* __restrict__ part,
                                                  const float* __restrict__ bo,
                                                  float* __restrict__ out, long n, int nslab) {
  long i = (long)blockIdx.x * 256 + threadIdx.x;
  if (i >= n) return;
  float v = bo[i & (D_ - 1)];
  for (int s = 0; s < nslab; ++s) v += part[(long)s * n + i];
  out[i] = v;
}

struct GemmArgs {
  const f16 *A, *Bm;
  void* C;
  const float* bias;
  unsigned* Mout;   // RMAX: per-row max (mapped uint), per-zloc stride sMz
  int K, lda, ldb, ldc;
  int zbase, NG, PBG;
  long sAp, sAb, sAg, sAz;
  long sBp, sBb, sBg, sBz;
  long sCp, sCb, sCg, sCz;
  long sbp, sbb, sbg, sbz;
  long sMz;
};

// NT GEMM fp16: C[m][n] = sum_k A[m][k]*B[n][k], fp32 acc. Swizzle s(r)=(r>>1)&3
// (2-way = free; verified round 10: conflicts 8.4M -> 0). RMAX: epilogue
// computes per-row max via shfl + atomicMax(mapped).
template <typename OutT, int BIAS, bool RMAX>
__global__ __launch_bounds__(256) void gemm_nt(GemmArgs p) {
  int zloc = blockIdx.z;
  int zi = p.zbase + zloc;
  int pp = zi / p.PBG; int rz = zi - pp * p.PBG;
  int bb = rz / p.NG;  int g = rz - bb * p.NG;
  const f16* A  = p.A + (pp * p.sAp + bb * p.sAb + g * p.sAg + (long)zloc * p.sAz);
  const f16* Bm = p.Bm + (pp * p.sBp + bb * p.sBb + g * p.sBg + (long)zloc * p.sBz);
  OutT* C = (OutT*)p.C + (pp * p.sCp + bb * p.sCb + g * p.sCg + (long)zloc * p.sCz);
  const float* bias = nullptr;
  if (BIAS) bias = p.bias + (pp * p.sbp + bb * p.sbb + g * p.sbg + (long)zloc * p.sbz);
  unsigned* Mz = RMAX ? (p.Mout + (long)zloc * p.sMz) : nullptr;

  __shared__ f16 lA[4096];
  __shared__ f16 lB[4096];

  int tid = threadIdx.x;
  int lane = tid & 63;
  int w = tid >> 6;
  int wm = (w >> 1) << 6;
  int wn = (w & 1) << 6;
  long bm = (long)blockIdx.y * 128;
  long bn = (long)blockIdx.x * 128;

  f32x4 acc[4][4] = {};
  int qd = lane >> 4;
  int fr = lane & 15;

  int q0 = tid, q1 = tid + 256;
  int r0s = q0 >> 2, c0s = (q0 & 3) ^ ((r0s >> 1) & 3);
  int r1s = q1 >> 2, c1s = (q1 & 3) ^ ((r1s >> 1) & 3);

  for (int k0 = 0; k0 < p.K; k0 += 32) {
    long oa0 = (bm + r0s) * (long)p.lda + (k0 + c0s * 8);
    long oa1 = (bm + r1s) * (long)p.lda + (k0 + c1s * 8);
    long ob0 = (bn + r0s) * (long)p.ldb + (k0 + c0s * 8);
    long ob1 = (bn + r1s) * (long)p.ldb + (k0 + c1s * 8);
    __syncthreads();
    async_ld16(A + oa0,  lA + (size_t)q0 * 8);
    async_ld16(A + oa1,  lA + (size_t)q1 * 8);
    async_ld16(Bm + ob0, lB + (size_t)q0 * 8);
    async_ld16(Bm + ob1, lB + (size_t)q1 * 8);
    __syncthreads();

    f16x8 ah[4], bh[4];
#pragma unroll
    for (int i = 0; i < 4; ++i) {
      int m = wm + i * 16 + fr;
      ah[i] = *(const f16x8*)(lA + ((size_t)m * 4 + (qd ^ ((m >> 1) & 3))) * 8);
      int n = wn + i * 16 + fr;
      bh[i] = *(const f16x8*)(lB + ((size_t)n * 4 + (qd ^ ((n >> 1) & 3))) * 8);
    }
#pragma unroll
    for (int i = 0; i < 4; ++i)
#pragma unroll
      for (int j = 0; j < 4; ++j)
        acc[i][j] = __builtin_amdgcn_mfma_f32_16x16x32_f16(ah[i], bh[j], acc[i][j], 0, 0, 0);
  }

  int rr0 = (lane >> 4) * 4;
#pragma unroll
  for (int i = 0; i < 4; ++i) {
#pragma unroll
    for (int j = 0; j < 4; ++j) {
#pragma unroll
      for (int r = 0; r < 4; ++r) {
        long row = bm + wm + i * 16 + rr0 + r;
        long col = bn + wn + j * 16 + fr;
        float v = acc[i][j][r];
        if (BIAS == 1) v += bias[col];
        if (BIAS == 2) v += bias[row];
        C[row * (long)p.ldc + col] = (OutT)v;
      }
    }
  }
  if (RMAX) {
#pragma unroll
    for (int i = 0; i < 4; ++i) {
#pragma unroll
      for (int r = 0; r < 4; ++r) {
        float pm = fmaxf(fmaxf(acc[i][0][r], acc[i][1][r]),
                         fmaxf(acc[i][2][r], acc[i][3][r]));
        pm = fmaxf(pm, __shfl_xor(pm, 1, 64));
        pm = fmaxf(pm, __shfl_xor(pm, 2, 64));
        pm = fmaxf(pm, __shfl_xor(pm, 4, 64));
        pm = fmaxf(pm, __shfl_xor(pm, 8, 64));
        if (fr == 0) atomicMax(Mz + (bm + wm + i * 16 + rr0 + r), fmap(pm));
      }
    }
  }
}

// Flash-PV: O[s][e] = sum_t exp(S[s][t]-m[s]) * V[e][t] / l[s].
// Per block: 128 s-rows x 128 e-cols, K-loop over t. S staged fp32 with
// swizzle slot = r*8 + ((c+r)&7) (2 lanes/bank-group = free); l accumulated
// via ones-vector MFMA (lands in C-layout, aligned with O rows).
struct PvArgs {
  const float* S; const unsigned* M; const f16* V; f16* C;
  int ldc, zbase, NG;
  long sVz, sCb, sCg;
};
__global__ __launch_bounds__(256) void pv_flash(PvArgs p) {
  int zloc = blockIdx.z;
  int zi = p.zbase + zloc;
  int bb = zi / p.NG; int g = zi - bb * p.NG;
  const float* Sm = p.S + (long)zloc * S_ * S_;
  const unsigned* Mz = p.M + (long)zloc * S_;
  const f16* V = p.V + (long)zloc * p.sVz;
  f16* C = p.C + bb * p.sCb + g * p.sCg;

  __shared__ float lS[4096];  // 128 rows x 8 chunks of f32x4 (16 KB)
  __shared__ f16 lV[4096];

  int tid = threadIdx.x;
  int lane = tid & 63;
  int w = tid >> 6;
  int wm = (w >> 1) << 6;
  int wn = (w & 1) << 6;
  long bm = (long)blockIdx.y * 128;
  long bn = (long)blockIdx.x * 128;

  int qd = lane >> 4;
  int fr = lane & 15;

  float mrow[4];
#pragma unroll
  for (int i = 0; i < 4; ++i) mrow[i] = funmap(Mz[bm + wm + i * 16 + fr]);

  f32x4 acc[4][4] = {};
  f32x4 lacc[4] = {};
  f16x8 ones;
#pragma unroll
  for (int j = 0; j < 8; ++j) ones[j] = (f16)1.0f;

  // V staging (as gemm B): chunk q holds row r=q>>2, kchunk c=(q&3)^((r>>1)&3)
  int q0 = tid, q1 = tid + 256;
  int r0v = q0 >> 2, c0v = (q0 & 3) ^ ((r0v >> 1) & 3);
  int r1v = q1 >> 2, c1v = (q1 & 3) ^ ((r1v >> 1) & 3);
  // S staging: 4 chunks/thread; slot q holds row r=q>>3, cglob=((q&7)-r)&7
  int rS[4], cS[4];
#pragma unroll
  for (int j = 0; j < 4; ++j) {
    int q = j * 256 + tid;
    rS[j] = q >> 3;
    cS[j] = ((q & 7) - rS[j]) & 7;
  }

  for (int k0 = 0; k0 < S_; k0 += 32) {
    __syncthreads();
#pragma unroll
    for (int j = 0; j < 4; ++j)
      async_ld16(Sm + (bm + rS[j]) * (long)S_ + (k0 + cS[j] * 4),
                 lS + (size_t)(j * 256 + tid) * 4);
    async_ld16(V + (bn + r0v) * (long)S_ + (k0 + c0v * 8), lV + (size_t)q0 * 8);
    async_ld16(V + (bn + r1v) * (long)S_ + (k0 + c1v * 8), lV + (size_t)q1 * 8);
    __syncthreads();

    f16x8 bh[4], ae[4];
#pragma unroll
    for (int j = 0; j < 4; ++j) {
      int n = wn + j * 16 + fr;
      bh[j] = *(const f16x8*)(lV + ((size_t)n * 4 + (qd ^ ((n >> 1) & 3))) * 8);
    }
#pragma unroll
    for (int i = 0; i < 4; ++i) {
      int m = wm + i * 16 + fr;
      f32x4 s0 = ((const f32x4*)lS)[m * 8 + ((2 * qd + m) & 7)];
      f32x4 s1 = ((const f32x4*)lS)[m * 8 + ((2 * qd + 1 + m) & 7)];
#pragma unroll
      for (int t = 0; t < 4; ++t) {
        ae[i][t]     = (f16)__expf(s0[t] - mrow[i]);
        ae[i][4 + t] = (f16)__expf(s1[t] - mrow[i]);
      }
    }
#pragma unroll
    for (int i = 0; i < 4; ++i) {
      lacc[i] = __builtin_amdgcn_mfma_f32_16x16x32_f16(ae[i], ones, lacc[i], 0, 0, 0);
#pragma unroll
      for (int j = 0; j < 4; ++j)
        acc[i][j] = __builtin_amdgcn_mfma_f32_16x16x32_f16(ae[i], bh[j], acc[i][j], 0, 0, 0);
    }
  }

  int rr0 = (lane >> 4) * 4;
#pragma unroll
  for (int i = 0; i < 4; ++i) {
    float inv[4];
#pragma unroll
    for (int r = 0; r < 4; ++r) inv[r] = 1.0f / lacc[i][r];
#pragma unroll
    for (int j = 0; j < 4; ++j) {
#pragma unroll
      for (int r = 0; r < 4; ++r) {
        long row = bm + wm + i * 16 + rr0 + r;
        long col = bn + wn + j * 16 + fr;
        C[row * (long)p.ldc + col] = (f16)(acc[i][j][r] * inv[r]);
      }
    }
  }
}

extern "C" void kernel_launch(void* const* d_in, const int* in_sizes, int n_in,
                              void* d_out, int out_size, void* d_ws, size_t ws_size,
                              hipStream_t stream) {
  const float* x  = (const float*)d_in[0];
  const float* Wq = (const float*)d_in[1];
  const float* bq = (const float*)d_in[2];
  const float* Wk = (const float*)d_in[3];
  const float* bk = (const float*)d_in[4];
  const float* Wv = (const float*)d_in[5];
  const float* bv = (const float*)d_in[6];
  const float* Wo = (const float*)d_in[7];
  const float* bo = (const float*)d_in[8];
  float* out = (float*)d_out;

  auto al = [](size_t v) { return (v + 255) & ~(size_t)255; };
  const size_t eX = (size_t)B_ * S_ * D_;
  const size_t eW = (size_t)H_ * D_ * D_;
  const size_t eSS = (size_t)S_ * S_;
  const long SD = (long)S_ * D_;
  const long DD = (long)D_ * D_;
  const long DS = (long)D_ * S_;

  size_t fixed = al(eX * 2) + al(2 * eW * 2) + al(eW * 2) + al(eW * 2)
               + al(2ULL * H_ * D_ * 4);
  int NB = 1, GH = 1, GS = 1; bool found = false;
  for (int nb = 2; nb >= 1 && !found; --nb)
    for (int gh = 8; gh >= 1 && !found; gh >>= 1)
      for (int gs = nb * gh; gs >= 1 && !found; gs >>= 1) {
        size_t need = fixed + al((size_t)nb * S_ * H_ * D_ * 2)
                    + al(2ULL * nb * gh * S_ * D_ * 2)
                    + al((size_t)nb * gh * D_ * S_ * 2)
                    + al(4ULL * nb * SD * 4)
                    + al((size_t)gs * eSS * 4) + al((size_t)gs * S_ * 4);
        if (need <= ws_size) { NB = nb; GH = gh; GS = gs; found = true; }
      }

  char* p0 = (char*)d_ws;
  size_t off = 0;
  f16* xh    = (f16*)(p0 + off); off += al(eX * 2);
  f16* wqk   = (f16*)(p0 + off); off += al(2 * eW * 2);
  f16* wv    = (f16*)(p0 + off); off += al(eW * 2);
  f16* wo    = (f16*)(p0 + off); off += al(eW * 2);
  float* bqk = (float*)(p0 + off); off += al(2ULL * H_ * D_ * 4);
  f16* catb  = (f16*)(p0 + off); off += al((size_t)NB * S_ * H_ * D_ * 2);
  f16* qk    = (f16*)(p0 + off); off += al(2ULL * NB * GH * S_ * D_ * 2);
  f16* vT    = (f16*)(p0 + off); off += al((size_t)NB * GH * D_ * S_ * 2);
  float* opart = (float*)(p0 + off); off += al(4ULL * NB * SD * 4);
  float* scores = (float*)(p0 + off); off += al((size_t)GS * eSS * 4);
  unsigned* rowmax = (unsigned*)(p0 + off);

  // ---- prep ----
  cvt_f16<<<dim3((unsigned)((eX + 255) / 256)), 256, 0, stream>>>(x, xh, (long)eX);
  dim3 tb(32, 8, 1);
  transpose_f32<<<dim3(16, 16, H_), tb, 0, stream>>>(Wq, wqk, D_, D_);
  transpose_f32<<<dim3(16, 16, H_), tb, 0, stream>>>(Wk, wqk + eW, D_, D_);
  transpose_f32<<<dim3(16, 16, H_), tb, 0, stream>>>(Wv, wv, D_, D_);
  transpose_f32<<<dim3(16, 128, 1), tb, 0, stream>>>(Wo, wo, H_ * D_, D_);
  hipMemcpyAsync(bqk, bq, (size_t)H_ * D_ * 4, hipMemcpyDeviceToDevice, stream);
  hipMemcpyAsync(bqk + H_ * D_, bk, (size_t)H_ * D_ * 4, hipMemcpyDeviceToDevice, stream);

  for (int b0 = 0; b0 < B_; b0 += NB) {
    for (int h0 = 0; h0 < H_; h0 += GH) {
      {  // Q+K projections
        GemmArgs a{};
        a.A = xh + (long)b0 * SD;
        a.Bm = wqk + (long)h0 * DD;
        a.C = qk; a.bias = bqk + (long)h0 * D_;
        a.K = D_; a.lda = D_; a.ldb = D_; a.ldc = D_;
        a.zbase = 0; a.NG = GH; a.PBG = NB * GH;
        a.sAb = SD;
        a.sBp = (long)H_ * DD; a.sBg = DD;
        a.sCz = SD;
        a.sbp = (long)H_ * D_; a.sbg = D_;
        gemm_nt<f16, 1, false><<<dim3(4, 16, 2 * NB * GH), 256, 0, stream>>>(a);
      }
      {  // V^T
        GemmArgs a{};
        a.A = wv + (long)h0 * DD; a.Bm = xh + (long)b0 * SD;
        a.C = vT; a.bias = bv + (long)h0 * D_;
        a.K = D_; a.lda = D_; a.ldb = D_; a.ldc = S_;
        a.zbase = 0; a.NG = GH; a.PBG = NB * GH;
        a.sAg = DD;
        a.sBb = SD;
        a.sCz = DS;
        a.sbg = D_;
        gemm_nt<f16, 2, false><<<dim3(16, 4, NB * GH), 256, 0, stream>>>(a);
      }
      for (int g0 = 0; g0 < NB * GH; g0 += GS) {
        hipMemsetAsync(rowmax, 0, (size_t)GS * S_ * 4, stream);
        {  // scores = Q·K^T + row max
          GemmArgs a{};
          a.A = qk + (long)g0 * SD;
          a.Bm = qk + ((long)NB * GH + g0) * SD;
          a.C = scores; a.Mout = rowmax;
          a.K = D_; a.lda = D_; a.ldb = D_; a.ldc = S_;
          a.zbase = g0; a.NG = GH; a.PBG = NB * GH;
          a.sAz = SD; a.sBz = SD; a.sCz = (long)eSS; a.sMz = S_;
          gemm_nt<float, 0, true><<<dim3(16, 16, GS), 256, 0, stream>>>(a);
        }
        {  // flash PV: catb = softmax(scores)·V
          PvArgs a{};
          a.S = scores; a.M = rowmax; a.V = vT + (long)g0 * DS;
          a.C = catb + (long)h0 * D_;
          a.ldc = H_ * D_; a.zbase = g0; a.NG = GH;
          a.sVz = DS; a.sCb = (long)S_ * H_ * D_; a.sCg = D_;
          pv_flash<<<dim3(4, 16, GS), 256, 0, stream>>>(a);
        }
      }
    }
    {  // out-proj split-K
      GemmArgs a{};
      a.A = catb; a.Bm = wo;
      a.C = opart;
      a.K = 1024; a.lda = H_ * D_; a.ldb = H_ * D_; a.ldc = D_;
      a.zbase = 0; a.NG = 4; a.PBG = NB * 4;
      a.sAb = (long)S_ * H_ * D_; a.sAg = 1024;
      a.sBg = 1024;
      a.sCb = SD; a.sCg = (long)NB * SD;
      gemm_nt<float, 0, false><<<dim3(4, 16, NB * 4), 256, 0, stream>>>(a);
    }
    reduce_out<<<dim3((unsigned)(((long)NB * SD + 255) / 256)), 256, 0, stream>>>(
        opart, bo, out + (long)b0 * SD, (long)NB * SD, 4);
  }
}

// Round 13
// 573.490 us; speedup vs baseline: 2.8083x; 1.2526x over previous
//
#include <hip/hip_runtime.h>

typedef _Float16 f16;
typedef _Float16 f16x8 __attribute__((ext_vector_type(8)));
typedef float f32x4 __attribute__((ext_vector_type(4)));

#define B_ 2
#define S_ 2048
#define D_ 512
#define H_ 8

__device__ inline void async_ld16(const void* g, void* l) {
  __builtin_amdgcn_global_load_lds((__attribute__((address_space(1))) void*)(g),
                                   (__attribute__((address_space(3))) void*)(l),
                                   16, 0, 0);
}

// monotone uint mapping of fp32 for atomicMax-based row max
__device__ inline unsigned fmap(float f) {
  unsigned u = __float_as_uint(f);
  return (u & 0x80000000u) ? ~u : (u | 0x80000000u);
}
__device__ inline float funmap(unsigned k) {
  return (k & 0x80000000u) ? __uint_as_float(k ^ 0x80000000u) : __uint_as_float(~k);
}

__global__ __launch_bounds__(256) void cvt_f16(const float* __restrict__ src,
                                               f16* __restrict__ dst, long n) {
  long i = (long)blockIdx.x * 256 + threadIdx.x;
  if (i >= n) return;
  dst[i] = (f16)src[i];
}

// [z][R][C] fp32 -> [z][C][R] fp16
__global__ __launch_bounds__(256) void transpose_f32(const float* __restrict__ src,
                                                     f16* __restrict__ dst, int R, int C) {
  __shared__ float t[32][33];
  size_t zoff = (size_t)blockIdx.z * R * C;
  const float* s = src + zoff;
  int tx = threadIdx.x;
  int ty = threadIdx.y;
  int c0 = blockIdx.x * 32, r0 = blockIdx.y * 32;
#pragma unroll
  for (int i = 0; i < 4; ++i)
    t[ty + i * 8][tx] = s[(size_t)(r0 + ty + i * 8) * C + c0 + tx];
  __syncthreads();
#pragma unroll
  for (int i = 0; i < 4; ++i)
    dst[zoff + (size_t)(c0 + ty + i * 8) * R + r0 + tx] = (f16)t[tx][ty + i * 8];
}

// out[i] = bo[i%D] + sum over nslab split-K partial slabs
__global__ __launch_bounds__(256) void reduce_out(const float* __restrict__ part,
                                                  const float* __restrict__ bo,
                                                  float* __restrict__ out, long n, int nslab) {
  long i = (long)blockIdx.x * 256 + threadIdx.x;
  if (i >= n) return;
  float v = bo[i & (D_ - 1)];
  for (int s = 0; s < nslab; ++s) v += part[(long)s * n + i];
  out[i] = v;
}

struct GemmArgs {
  const f16 *A, *Bm;
  void* C;
  const float* bias;
  unsigned* Mout;
  int K, lda, ldb, ldc;
  int zbase, NG, PBG;
  long sAp, sAb, sAg, sAz;
  long sBp, sBb, sBg, sBz;
  long sCp, sCb, sCg, sCz;
  long sbp, sbb, sbg, sbz;
  long sMz;
};

// NT GEMM fp16, fp32 acc. Swizzle s(r)=(r>>1)&3 (2-way = free; verified r10).
// RMAX: epilogue row-max via shfl + atomicMax(mapped) from fp32 acc.
template <typename OutT, int BIAS, bool RMAX>
__global__ __launch_bounds__(256) void gemm_nt(GemmArgs p) {
  int zloc = blockIdx.z;
  int zi = p.zbase + zloc;
  int pp = zi / p.PBG; int rz = zi - pp * p.PBG;
  int bb = rz / p.NG;  int g = rz - bb * p.NG;
  const f16* A  = p.A + (pp * p.sAp + bb * p.sAb + g * p.sAg + (long)zloc * p.sAz);
  const f16* Bm = p.Bm + (pp * p.sBp + bb * p.sBb + g * p.sBg + (long)zloc * p.sBz);
  OutT* C = (OutT*)p.C + (pp * p.sCp + bb * p.sCb + g * p.sCg + (long)zloc * p.sCz);
  const float* bias = nullptr;
  if (BIAS) bias = p.bias + (pp * p.sbp + bb * p.sbb + g * p.sbg + (long)zloc * p.sbz);
  unsigned* Mz = RMAX ? (p.Mout + (long)zloc * p.sMz) : nullptr;

  __shared__ f16 lA[4096];
  __shared__ f16 lB[4096];

  int tid = threadIdx.x;
  int lane = tid & 63;
  int w = tid >> 6;
  int wm = (w >> 1) << 6;
  int wn = (w & 1) << 6;
  long bm = (long)blockIdx.y * 128;
  long bn = (long)blockIdx.x * 128;

  f32x4 acc[4][4] = {};
  int qd = lane >> 4;
  int fr = lane & 15;

  int q0 = tid, q1 = tid + 256;
  int r0s = q0 >> 2, c0s = (q0 & 3) ^ ((r0s >> 1) & 3);
  int r1s = q1 >> 2, c1s = (q1 & 3) ^ ((r1s >> 1) & 3);

  for (int k0 = 0; k0 < p.K; k0 += 32) {
    long oa0 = (bm + r0s) * (long)p.lda + (k0 + c0s * 8);
    long oa1 = (bm + r1s) * (long)p.lda + (k0 + c1s * 8);
    long ob0 = (bn + r0s) * (long)p.ldb + (k0 + c0s * 8);
    long ob1 = (bn + r1s) * (long)p.ldb + (k0 + c1s * 8);
    __syncthreads();
    async_ld16(A + oa0,  lA + (size_t)q0 * 8);
    async_ld16(A + oa1,  lA + (size_t)q1 * 8);
    async_ld16(Bm + ob0, lB + (size_t)q0 * 8);
    async_ld16(Bm + ob1, lB + (size_t)q1 * 8);
    __syncthreads();

    f16x8 ah[4], bh[4];
#pragma unroll
    for (int i = 0; i < 4; ++i) {
      int m = wm + i * 16 + fr;
      ah[i] = *(const f16x8*)(lA + ((size_t)m * 4 + (qd ^ ((m >> 1) & 3))) * 8);
      int n = wn + i * 16 + fr;
      bh[i] = *(const f16x8*)(lB + ((size_t)n * 4 + (qd ^ ((n >> 1) & 3))) * 8);
    }
#pragma unroll
    for (int i = 0; i < 4; ++i)
#pragma unroll
      for (int j = 0; j < 4; ++j)
        acc[i][j] = __builtin_amdgcn_mfma_f32_16x16x32_f16(ah[i], bh[j], acc[i][j], 0, 0, 0);
  }

  int rr0 = (lane >> 4) * 4;
#pragma unroll
  for (int i = 0; i < 4; ++i) {
#pragma unroll
    for (int j = 0; j < 4; ++j) {
#pragma unroll
      for (int r = 0; r < 4; ++r) {
        long row = bm + wm + i * 16 + rr0 + r;
        long col = bn + wn + j * 16 + fr;
        float v = acc[i][j][r];
        if (BIAS == 1) v += bias[col];
        if (BIAS == 2) v += bias[row];
        C[row * (long)p.ldc + col] = (OutT)v;
      }
    }
  }
  if (RMAX) {
#pragma unroll
    for (int i = 0; i < 4; ++i) {
#pragma unroll
      for (int r = 0; r < 4; ++r) {
        float pm = fmaxf(fmaxf(acc[i][0][r], acc[i][1][r]),
                         fmaxf(acc[i][2][r], acc[i][3][r]));
        pm = fmaxf(pm, __shfl_xor(pm, 1, 64));
        pm = fmaxf(pm, __shfl_xor(pm, 2, 64));
        pm = fmaxf(pm, __shfl_xor(pm, 4, 64));
        pm = fmaxf(pm, __shfl_xor(pm, 8, 64));
        if (fr == 0) atomicMax(Mz + (bm + wm + i * 16 + rr0 + r), fmap(pm));
      }
    }
  }
}

// Flash-PV, exp-once design: block = 64 s-rows x 512 e-cols; 4 waves split e.
// Cooperative exp phase: staged S (f16) is read/exp'd/written LINEARLY in tid
// (staging swizzle and P-layout swizzle compose to identity), producing the
// f16 P tile in A-fragment layout once per element; all 4 waves MFMA from it.
struct PvArgs {
  const f16* S; const unsigned* M; const f16* V; f16* C;
  int ldc, zbase, NG;
  long sVz, sCb, sCg;
};
__global__ __launch_bounds__(256) void pv_flash(PvArgs p) {
  int zloc = blockIdx.z;
  int zi = p.zbase + zloc;
  int bb = zi / p.NG; int g = zi - bb * p.NG;
  const f16* Sm = p.S + (long)zloc * S_ * S_;
  const unsigned* Mz = p.M + (long)zloc * S_;
  const f16* V = p.V + (long)zloc * p.sVz;
  f16* C = p.C + bb * p.sCb + g * p.sCg;

  __shared__ f16 lS[64 * 32];    // staged raw S (swizzled chunk layout)
  __shared__ f16 lP[64 * 32];    // exp'd P, A-fragment layout
  __shared__ f16 lV[512 * 32];   // V tile, B-fragment layout
  __shared__ float lM[64];

  int tid = threadIdx.x;
  int lane = tid & 63;
  int w = tid >> 6;
  long bm = (long)blockIdx.y * 64;  // s-row origin
  int e0 = w << 7;                  // wave's 128-col e origin

  int qd = lane >> 4;
  int fr = lane & 15;

  if (tid < 64) lM[tid] = funmap(Mz[bm + tid]);

  f32x4 acc[4][8] = {};
  f32x4 lacc[4] = {};
  f16x8 ones;
#pragma unroll
  for (int j = 0; j < 8; ++j) ones[j] = (f16)1.0f;

  int rs = tid >> 2, cs = (tid & 3) ^ ((rs >> 1) & 3);  // S staging map
  float mrow = 0.0f;  // set after first barrier

  __syncthreads();  // lM ready
  mrow = lM[tid >> 2];

  for (int k0 = 0; k0 < S_; k0 += 32) {
    __syncthreads();  // prior fragment reads done
    async_ld16(Sm + (bm + rs) * (long)S_ + (k0 + cs * 8), lS + (size_t)tid * 8);
#pragma unroll
    for (int j = 0; j < 8; ++j) {
      int q = j * 256 + tid;
      int rv = q >> 2, cv = (q & 3) ^ ((rv >> 1) & 3);
      async_ld16(V + rv * (long)S_ + (k0 + cv * 8), lV + (size_t)q * 8);
    }
    __syncthreads();  // staged

    {  // exp phase: slot tid -> slot tid (layouts compose to identity)
      f16x8 sv = *(const f16x8*)(lS + (size_t)tid * 8);
      f16x8 pv;
#pragma unroll
      for (int j = 0; j < 8; ++j) pv[j] = (f16)__expf((float)sv[j] - mrow);
      *(f16x8*)(lP + (size_t)tid * 8) = pv;
    }
    __syncthreads();  // P ready

    f16x8 ah[4], bh[8];
#pragma unroll
    for (int i = 0; i < 4; ++i) {
      int m = i * 16 + fr;
      ah[i] = *(const f16x8*)(lP + ((size_t)m * 4 + (qd ^ ((m >> 1) & 3))) * 8);
    }
#pragma unroll
    for (int j = 0; j < 8; ++j) {
      int n = e0 + j * 16 + fr;
      bh[j] = *(const f16x8*)(lV + ((size_t)n * 4 + (qd ^ ((n >> 1) & 3))) * 8);
    }
#pragma unroll
    for (int i = 0; i < 4; ++i) {
      lacc[i] = __builtin_amdgcn_mfma_f32_16x16x32_f16(ah[i], ones, lacc[i], 0, 0, 0);
#pragma unroll
      for (int j = 0; j < 8; ++j)
        acc[i][j] = __builtin_amdgcn_mfma_f32_16x16x32_f16(ah[i], bh[j], acc[i][j], 0, 0, 0);
    }
  }

  int rr0 = (lane >> 4) * 4;
#pragma unroll
  for (int i = 0; i < 4; ++i) {
    float inv[4];
#pragma unroll
    for (int r = 0; r < 4; ++r) inv[r] = 1.0f / lacc[i][r];
#pragma unroll
    for (int j = 0; j < 8; ++j) {
#pragma unroll
      for (int r = 0; r < 4; ++r) {
        long row = bm + i * 16 + rr0 + r;
        long col = e0 + j * 16 + fr;
        C[row * (long)p.ldc + col] = (f16)(acc[i][j][r] * inv[r]);
      }
    }
  }
}

extern "C" void kernel_launch(void* const* d_in, const int* in_sizes, int n_in,
                              void* d_out, int out_size, void* d_ws, size_t ws_size,
                              hipStream_t stream) {
  const float* x  = (const float*)d_in[0];
  const float* Wq = (const float*)d_in[1];
  const float* bq = (const float*)d_in[2];
  const float* Wk = (const float*)d_in[3];
  const float* bk = (const float*)d_in[4];
  const float* Wv = (const float*)d_in[5];
  const float* bv = (const float*)d_in[6];
  const float* Wo = (const float*)d_in[7];
  const float* bo = (const float*)d_in[8];
  float* out = (float*)d_out;

  auto al = [](size_t v) { return (v + 255) & ~(size_t)255; };
  const size_t eX = (size_t)B_ * S_ * D_;
  const size_t eW = (size_t)H_ * D_ * D_;
  const size_t eSS = (size_t)S_ * S_;
  const long SD = (long)S_ * D_;
  const long DD = (long)D_ * D_;
  const long DS = (long)D_ * S_;

  size_t fixed = al(eX * 2) + al(2 * eW * 2) + al(eW * 2) + al(eW * 2)
               + al(2ULL * H_ * D_ * 4);
  int NB = 1, GH = 1, GS = 1; bool found = false;
  for (int nb = 2; nb >= 1 && !found; --nb)
    for (int gh = 8; gh >= 1 && !found; gh >>= 1)
      for (int gs = nb * gh; gs >= 1 && !found; gs >>= 1) {
        size_t need = fixed + al((size_t)nb * S_ * H_ * D_ * 2)
                    + al(2ULL * nb * gh * S_ * D_ * 2)
                    + al((size_t)nb * gh * D_ * S_ * 2)
                    + al(2ULL * nb * SD * 4)
                    + al((size_t)gs * eSS * 2) + al((size_t)gs * S_ * 4);
        if (need <= ws_size) { NB = nb; GH = gh; GS = gs; found = true; }
      }

  char* p0 = (char*)d_ws;
  size_t off = 0;
  f16* xh    = (f16*)(p0 + off); off += al(eX * 2);
  f16* wqk   = (f16*)(p0 + off); off += al(2 * eW * 2);
  f16* wv    = (f16*)(p0 + off); off += al(eW * 2);
  f16* wo    = (f16*)(p0 + off); off += al(eW * 2);
  float* bqk = (float*)(p0 + off); off += al(2ULL * H_ * D_ * 4);
  f16* catb  = (f16*)(p0 + off); off += al((size_t)NB * S_ * H_ * D_ * 2);
  f16* qk    = (f16*)(p0 + off); off += al(2ULL * NB * GH * S_ * D_ * 2);
  f16* vT    = (f16*)(p0 + off); off += al((size_t)NB * GH * D_ * S_ * 2);
  float* opart = (float*)(p0 + off); off += al(2ULL * NB * SD * 4);
  f16* scores = (f16*)(p0 + off); off += al((size_t)GS * eSS * 2);
  unsigned* rowmax = (unsigned*)(p0 + off);

  // ---- prep ----
  cvt_f16<<<dim3((unsigned)((eX + 255) / 256)), 256, 0, stream>>>(x, xh, (long)eX);
  dim3 tb(32, 8, 1);
  transpose_f32<<<dim3(16, 16, H_), tb, 0, stream>>>(Wq, wqk, D_, D_);
  transpose_f32<<<dim3(16, 16, H_), tb, 0, stream>>>(Wk, wqk + eW, D_, D_);
  transpose_f32<<<dim3(16, 16, H_), tb, 0, stream>>>(Wv, wv, D_, D_);
  transpose_f32<<<dim3(16, 128, 1), tb, 0, stream>>>(Wo, wo, H_ * D_, D_);
  hipMemcpyAsync(bqk, bq, (size_t)H_ * D_ * 4, hipMemcpyDeviceToDevice, stream);
  hipMemcpyAsync(bqk + H_ * D_, bk, (size_t)H_ * D_ * 4, hipMemcpyDeviceToDevice, stream);

  for (int b0 = 0; b0 < B_; b0 += NB) {
    for (int h0 = 0; h0 < H_; h0 += GH) {
      {  // Q+K projections
        GemmArgs a{};
        a.A = xh + (long)b0 * SD;
        a.Bm = wqk + (long)h0 * DD;
        a.C = qk; a.bias = bqk + (long)h0 * D_;
        a.K = D_; a.lda = D_; a.ldb = D_; a.ldc = D_;
        a.zbase = 0; a.NG = GH; a.PBG = NB * GH;
        a.sAb = SD;
        a.sBp = (long)H_ * DD; a.sBg = DD;
        a.sCz = SD;
        a.sbp = (long)H_ * D_; a.sbg = D_;
        gemm_nt<f16, 1, false><<<dim3(4, 16, 2 * NB * GH), 256, 0, stream>>>(a);
      }
      {  // V^T
        GemmArgs a{};
        a.A = wv + (long)h0 * DD; a.Bm = xh + (long)b0 * SD;
        a.C = vT; a.bias = bv + (long)h0 * D_;
        a.K = D_; a.lda = D_; a.ldb = D_; a.ldc = S_;
        a.zbase = 0; a.NG = GH; a.PBG = NB * GH;
        a.sAg = DD;
        a.sBb = SD;
        a.sCz = DS;
        a.sbg = D_;
        gemm_nt<f16, 2, false><<<dim3(16, 4, NB * GH), 256, 0, stream>>>(a);
      }
      for (int g0 = 0; g0 < NB * GH; g0 += GS) {
        hipMemsetAsync(rowmax, 0, (size_t)GS * S_ * 4, stream);
        {  // scores = Q·K^T (f16 out) + fp32 row max
          GemmArgs a{};
          a.A = qk + (long)g0 * SD;
          a.Bm = qk + ((long)NB * GH + g0) * SD;
          a.C = scores; a.Mout = rowmax;
          a.K = D_; a.lda = D_; a.ldb = D_; a.ldc = S_;
          a.zbase = g0; a.NG = GH; a.PBG = NB * GH;
          a.sAz = SD; a.sBz = SD; a.sCz = (long)eSS; a.sMz = S_;
          gemm_nt<f16, 0, true><<<dim3(16, 16, GS), 256, 0, stream>>>(a);
        }
        {  // flash PV (exp-once): catb = softmax(scores)·V
          PvArgs a{};
          a.S = scores; a.M = rowmax; a.V = vT + (long)g0 * DS;
          a.C = catb + (long)h0 * D_;
          a.ldc = H_ * D_; a.zbase = g0; a.NG = GH;
          a.sVz = DS; a.sCb = (long)S_ * H_ * D_; a.sCg = D_;
          pv_flash<<<dim3(1, S_ / 64, GS), 256, 0, stream>>>(a);
        }
      }
    }
    {  // out-proj split-K (2 slabs of 2048)
      GemmArgs a{};
      a.A = catb; a.Bm = wo;
      a.C = opart;
      a.K = 2048; a.lda = H_ * D_; a.ldb = H_ * D_; a.ldc = D_;
      a.zbase = 0; a.NG = 2; a.PBG = NB * 2;
      a.sAb = (long)S_ * H_ * D_; a.sAg = 2048;
      a.sBg = 2048;
      a.sCb = SD; a.sCg = (long)NB * SD;
      gemm_nt<float, 0, false><<<dim3(4, 16, NB * 2), 256, 0, stream>>>(a);
    }
    reduce_out<<<dim3((unsigned)(((long)NB * SD + 255) / 256)), 256, 0, stream>>>(
        opart, bo, out + (long)b0 * SD, (long)NB * SD, 2);
  }
}

// Round 14
// 555.710 us; speedup vs baseline: 2.8982x; 1.0320x over previous
//
#include <hip/hip_runtime.h>

typedef _Float16 f16;
typedef _Float16 f16x8 __attribute__((ext_vector_type(8)));
typedef float f32x4 __attribute__((ext_vector_type(4)));

#define B_ 2
#define S_ 2048
#define D_ 512
#define H_ 8

__device__ inline void async_ld16(const void* g, void* l) {
  __builtin_amdgcn_global_load_lds((__attribute__((address_space(1))) void*)(g),
                                   (__attribute__((address_space(3))) void*)(l),
                                   16, 0, 0);
}

// monotone uint mapping of fp32 for atomicMax-based row max
__device__ inline unsigned fmap(float f) {
  unsigned u = __float_as_uint(f);
  return (u & 0x80000000u) ? ~u : (u | 0x80000000u);
}
__device__ inline float funmap(unsigned k) {
  return (k & 0x80000000u) ? __uint_as_float(k ^ 0x80000000u) : __uint_as_float(~k);
}

__global__ __launch_bounds__(256) void cvt_f16(const float* __restrict__ src,
                                               f16* __restrict__ dst, long n) {
  long i = (long)blockIdx.x * 256 + threadIdx.x;
  if (i >= n) return;
  dst[i] = (f16)src[i];
}

// [z][R][C] fp32 -> [z][C][R] fp16
__global__ __launch_bounds__(256) void transpose_f32(const float* __restrict__ src,
                                                     f16* __restrict__ dst, int R, int C) {
  __shared__ float t[32][33];
  size_t zoff = (size_t)blockIdx.z * R * C;
  const float* s = src + zoff;
  int tx = threadIdx.x;
  int ty = threadIdx.y;
  int c0 = blockIdx.x * 32, r0 = blockIdx.y * 32;
#pragma unroll
  for (int i = 0; i < 4; ++i)
    t[ty + i * 8][tx] = s[(size_t)(r0 + ty + i * 8) * C + c0 + tx];
  __syncthreads();
#pragma unroll
  for (int i = 0; i < 4; ++i)
    dst[zoff + (size_t)(c0 + ty + i * 8) * R + r0 + tx] = (f16)t[tx][ty + i * 8];
}

// out[i] = bo[i%D] + sum over nslab split-K partial slabs
__global__ __launch_bounds__(256) void reduce_out(const float* __restrict__ part,
                                                  const float* __restrict__ bo,
                                                  float* __restrict__ out, long n, int nslab) {
  long i = (long)blockIdx.x * 256 + threadIdx.x;
  if (i >= n) return;
  float v = bo[i & (D_ - 1)];
  for (int s = 0; s < nslab; ++s) v += part[(long)s * n + i];
  out[i] = v;
}

struct GemmArgs {
  const f16 *A, *Bm;
  void* C;
  const float* bias;
  unsigned* Mout;
  int K, lda, ldb, ldc;
  int zbase, NG, PBG;
  long sAp, sAb, sAg, sAz;
  long sBp, sBb, sBg, sBz;
  long sCp, sCb, sCg, sCz;
  long sbp, sbb, sbg, sbz;
  long sMz;
};

// NT GEMM fp16, fp32 acc. Swizzle s(r)=(r>>1)&3 (2-way = free; verified r10).
// RMAX: epilogue row-max via shfl + atomicMax(mapped) from fp32 acc.
template <typename OutT, int BIAS, bool RMAX>
__global__ __launch_bounds__(256) void gemm_nt(GemmArgs p) {
  int zloc = blockIdx.z;
  int zi = p.zbase + zloc;
  int pp = zi / p.PBG; int rz = zi - pp * p.PBG;
  int bb = rz / p.NG;  int g = rz - bb * p.NG;
  const f16* A  = p.A + (pp * p.sAp + bb * p.sAb + g * p.sAg + (long)zloc * p.sAz);
  const f16* Bm = p.Bm + (pp * p.sBp + bb * p.sBb + g * p.sBg + (long)zloc * p.sBz);
  OutT* C = (OutT*)p.C + (pp * p.sCp + bb * p.sCb + g * p.sCg + (long)zloc * p.sCz);
  const float* bias = nullptr;
  if (BIAS) bias = p.bias + (pp * p.sbp + bb * p.sbb + g * p.sbg + (long)zloc * p.sbz);
  unsigned* Mz = RMAX ? (p.Mout + (long)zloc * p.sMz) : nullptr;

  __shared__ f16 lA[4096];
  __shared__ f16 lB[4096];

  int tid = threadIdx.x;
  int lane = tid & 63;
  int w = tid >> 6;
  int wm = (w >> 1) << 6;
  int wn = (w & 1) << 6;
  long bm = (long)blockIdx.y * 128;
  long bn = (long)blockIdx.x * 128;

  f32x4 acc[4][4] = {};
  int qd = lane >> 4;
  int fr = lane & 15;

  int q0 = tid, q1 = tid + 256;
  int r0s = q0 >> 2, c0s = (q0 & 3) ^ ((r0s >> 1) & 3);
  int r1s = q1 >> 2, c1s = (q1 & 3) ^ ((r1s >> 1) & 3);

  for (int k0 = 0; k0 < p.K; k0 += 32) {
    long oa0 = (bm + r0s) * (long)p.lda + (k0 + c0s * 8);
    long oa1 = (bm + r1s) * (long)p.lda + (k0 + c1s * 8);
    long ob0 = (bn + r0s) * (long)p.ldb + (k0 + c0s * 8);
    long ob1 = (bn + r1s) * (long)p.ldb + (k0 + c1s * 8);
    __syncthreads();
    async_ld16(A + oa0,  lA + (size_t)q0 * 8);
    async_ld16(A + oa1,  lA + (size_t)q1 * 8);
    async_ld16(Bm + ob0, lB + (size_t)q0 * 8);
    async_ld16(Bm + ob1, lB + (size_t)q1 * 8);
    __syncthreads();

    f16x8 ah[4], bh[4];
#pragma unroll
    for (int i = 0; i < 4; ++i) {
      int m = wm + i * 16 + fr;
      ah[i] = *(const f16x8*)(lA + ((size_t)m * 4 + (qd ^ ((m >> 1) & 3))) * 8);
      int n = wn + i * 16 + fr;
      bh[i] = *(const f16x8*)(lB + ((size_t)n * 4 + (qd ^ ((n >> 1) & 3))) * 8);
    }
#pragma unroll
    for (int i = 0; i < 4; ++i)
#pragma unroll
      for (int j = 0; j < 4; ++j)
        acc[i][j] = __builtin_amdgcn_mfma_f32_16x16x32_f16(ah[i], bh[j], acc[i][j], 0, 0, 0);
  }

  int rr0 = (lane >> 4) * 4;
#pragma unroll
  for (int i = 0; i < 4; ++i) {
#pragma unroll
    for (int j = 0; j < 4; ++j) {
#pragma unroll
      for (int r = 0; r < 4; ++r) {
        long row = bm + wm + i * 16 + rr0 + r;
        long col = bn + wn + j * 16 + fr;
        float v = acc[i][j][r];
        if (BIAS == 1) v += bias[col];
        if (BIAS == 2) v += bias[row];
        C[row * (long)p.ldc + col] = (OutT)v;
      }
    }
  }
  if (RMAX) {
#pragma unroll
    for (int i = 0; i < 4; ++i) {
#pragma unroll
      for (int r = 0; r < 4; ++r) {
        float pm = fmaxf(fmaxf(acc[i][0][r], acc[i][1][r]),
                         fmaxf(acc[i][2][r], acc[i][3][r]));
        pm = fmaxf(pm, __shfl_xor(pm, 1, 64));
        pm = fmaxf(pm, __shfl_xor(pm, 2, 64));
        pm = fmaxf(pm, __shfl_xor(pm, 4, 64));
        pm = fmaxf(pm, __shfl_xor(pm, 8, 64));
        if (fr == 0) atomicMax(Mz + (bm + wm + i * 16 + rr0 + r), fmap(pm));
      }
    }
  }
}

// Flash-PV: block = 64 s-rows x 256 e-cols (4 waves x 64 cols), grid
// (2, 32, GS) ~= 512+ blocks -> 2+ blocks/CU so stage/exp/MFMA phases of
// different blocks overlap (r13's 64x512 ran 1 block/CU, occupancy 10.6%,
// MfmaUtil 14.7% — barrier-serialized). Cooperative exp phase is slot-
// identity (staging swizzle == P-fragment swizzle); l via ones-MFMA.
struct PvArgs {
  const f16* S; const unsigned* M; const f16* V; f16* C;
  int ldc, zbase, NG;
  long sVz, sCb, sCg;
};
__global__ __launch_bounds__(256) void pv_flash(PvArgs p) {
  int zloc = blockIdx.z;
  int zi = p.zbase + zloc;
  int bb = zi / p.NG; int g = zi - bb * p.NG;
  const f16* Sm = p.S + (long)zloc * S_ * S_;
  const unsigned* Mz = p.M + (long)zloc * S_;
  const f16* V = p.V + (long)zloc * p.sVz;
  f16* C = p.C + bb * p.sCb + g * p.sCg;

  __shared__ f16 lS[64 * 32];    // staged raw S (swizzled chunk layout) 4 KB
  __shared__ f16 lP[64 * 32];    // exp'd P, A-fragment layout 4 KB
  __shared__ f16 lV[256 * 32];   // V tile, B-fragment layout 16 KB

  int tid = threadIdx.x;
  int lane = tid & 63;
  int w = tid >> 6;
  long bm = (long)blockIdx.y * 64;   // s-row origin
  long bn = (long)blockIdx.x * 256;  // e origin of the block
  int e0 = w << 6;                   // wave's 64-col e origin within block

  int qd = lane >> 4;
  int fr = lane & 15;

  f32x4 acc[4][4] = {};
  f32x4 lacc[4] = {};
  f16x8 ones;
#pragma unroll
  for (int j = 0; j < 8; ++j) ones[j] = (f16)1.0f;

  int rs = tid >> 2, cs = (tid & 3) ^ ((rs >> 1) & 3);  // S staging map
  float mrow = funmap(Mz[bm + rs]);                     // row max for exp phase

  for (int k0 = 0; k0 < S_; k0 += 32) {
    __syncthreads();  // prior fragment reads done
    async_ld16(Sm + (bm + rs) * (long)S_ + (k0 + cs * 8), lS + (size_t)tid * 8);
#pragma unroll
    for (int j = 0; j < 4; ++j) {
      int q = j * 256 + tid;
      int rv = q >> 2, cv = (q & 3) ^ ((rv >> 1) & 3);
      async_ld16(V + (bn + rv) * (long)S_ + (k0 + cv * 8), lV + (size_t)q * 8);
    }
    __syncthreads();  // staged

    {  // exp phase: slot tid -> slot tid (layouts compose to identity)
      f16x8 sv = *(const f16x8*)(lS + (size_t)tid * 8);
      f16x8 pv;
#pragma unroll
      for (int j = 0; j < 8; ++j) pv[j] = (f16)__expf((float)sv[j] - mrow);
      *(f16x8*)(lP + (size_t)tid * 8) = pv;
    }
    __syncthreads();  // P ready

    f16x8 ah[4], bh[4];
#pragma unroll
    for (int i = 0; i < 4; ++i) {
      int m = i * 16 + fr;
      ah[i] = *(const f16x8*)(lP + ((size_t)m * 4 + (qd ^ ((m >> 1) & 3))) * 8);
    }
#pragma unroll
    for (int j = 0; j < 4; ++j) {
      int n = e0 + j * 16 + fr;
      bh[j] = *(const f16x8*)(lV + ((size_t)n * 4 + (qd ^ ((n >> 1) & 3))) * 8);
    }
#pragma unroll
    for (int i = 0; i < 4; ++i) {
      lacc[i] = __builtin_amdgcn_mfma_f32_16x16x32_f16(ah[i], ones, lacc[i], 0, 0, 0);
#pragma unroll
      for (int j = 0; j < 4; ++j)
        acc[i][j] = __builtin_amdgcn_mfma_f32_16x16x32_f16(ah[i], bh[j], acc[i][j], 0, 0, 0);
    }
  }

  int rr0 = (lane >> 4) * 4;
#pragma unroll
  for (int i = 0; i < 4; ++i) {
    float inv[4];
#pragma unroll
    for (int r = 0; r < 4; ++r) inv[r] = 1.0f / lacc[i][r];
#pragma unroll
    for (int j = 0; j < 4; ++j) {
#pragma unroll
      for (int r = 0; r < 4; ++r) {
        long row = bm + i * 16 + rr0 + r;
        long col = bn + e0 + j * 16 + fr;
        C[row * (long)p.ldc + col] = (f16)(acc[i][j][r] * inv[r]);
      }
    }
  }
}

extern "C" void kernel_launch(void* const* d_in, const int* in_sizes, int n_in,
                              void* d_out, int out_size, void* d_ws, size_t ws_size,
                              hipStream_t stream) {
  const float* x  = (const float*)d_in[0];
  const float* Wq = (const float*)d_in[1];
  const float* bq = (const float*)d_in[2];
  const float* Wk = (const float*)d_in[3];
  const float* bk = (const float*)d_in[4];
  const float* Wv = (const float*)d_in[5];
  const float* bv = (const float*)d_in[6];
  const float* Wo = (const float*)d_in[7];
  const float* bo = (const float*)d_in[8];
  float* out = (float*)d_out;

  auto al = [](size_t v) { return (v + 255) & ~(size_t)255; };
  const size_t eX = (size_t)B_ * S_ * D_;
  const size_t eW = (size_t)H_ * D_ * D_;
  const size_t eSS = (size_t)S_ * S_;
  const long SD = (long)S_ * D_;
  const long DD = (long)D_ * D_;
  const long DS = (long)D_ * S_;

  size_t fixed = al(eX * 2) + al(2 * eW * 2) + al(eW * 2) + al(eW * 2)
               + al(2ULL * H_ * D_ * 4);
  int NB = 1, GH = 1, GS = 1; bool found = false;
  for (int nb = 2; nb >= 1 && !found; --nb)
    for (int gh = 8; gh >= 1 && !found; gh >>= 1)
      for (int gs = nb * gh; gs >= 1 && !found; gs >>= 1) {
        size_t need = fixed + al((size_t)nb * S_ * H_ * D_ * 2)
                    + al(2ULL * nb * gh * S_ * D_ * 2)
                    + al((size_t)nb * gh * D_ * S_ * 2)
                    + al(2ULL * nb * SD * 4)
                    + al((size_t)gs * eSS * 2) + al((size_t)gs * S_ * 4);
        if (need <= ws_size) { NB = nb; GH = gh; GS = gs; found = true; }
      }

  char* p0 = (char*)d_ws;
  size_t off = 0;
  f16* xh    = (f16*)(p0 + off); off += al(eX * 2);
  f16* wqk   = (f16*)(p0 + off); off += al(2 * eW * 2);
  f16* wv    = (f16*)(p0 + off); off += al(eW * 2);
  f16* wo    = (f16*)(p0 + off); off += al(eW * 2);
  float* bqk = (float*)(p0 + off); off += al(2ULL * H_ * D_ * 4);
  f16* catb  = (f16*)(p0 + off); off += al((size_t)NB * S_ * H_ * D_ * 2);
  f16* qk    = (f16*)(p0 + off); off += al(2ULL * NB * GH * S_ * D_ * 2);
  f16* vT    = (f16*)(p0 + off); off += al((size_t)NB * GH * D_ * S_ * 2);
  float* opart = (float*)(p0 + off); off += al(2ULL * NB * SD * 4);
  f16* scores = (f16*)(p0 + off); off += al((size_t)GS * eSS * 2);
  unsigned* rowmax = (unsigned*)(p0 + off);

  // ---- prep ----
  cvt_f16<<<dim3((unsigned)((eX + 255) / 256)), 256, 0, stream>>>(x, xh, (long)eX);
  dim3 tb(32, 8, 1);
  transpose_f32<<<dim3(16, 16, H_), tb, 0, stream>>>(Wq, wqk, D_, D_);
  transpose_f32<<<dim3(16, 16, H_), tb, 0, stream>>>(Wk, wqk + eW, D_, D_);
  transpose_f32<<<dim3(16, 16, H_), tb, 0, stream>>>(Wv, wv, D_, D_);
  transpose_f32<<<dim3(16, 128, 1), tb, 0, stream>>>(Wo, wo, H_ * D_, D_);
  hipMemcpyAsync(bqk, bq, (size_t)H_ * D_ * 4, hipMemcpyDeviceToDevice, stream);
  hipMemcpyAsync(bqk + H_ * D_, bk, (size_t)H_ * D_ * 4, hipMemcpyDeviceToDevice, stream);

  for (int b0 = 0; b0 < B_; b0 += NB) {
    for (int h0 = 0; h0 < H_; h0 += GH) {
      {  // Q+K projections
        GemmArgs a{};
        a.A = xh + (long)b0 * SD;
        a.Bm = wqk + (long)h0 * DD;
        a.C = qk; a.bias = bqk + (long)h0 * D_;
        a.K = D_; a.lda = D_; a.ldb = D_; a.ldc = D_;
        a.zbase = 0; a.NG = GH; a.PBG = NB * GH;
        a.sAb = SD;
        a.sBp = (long)H_ * DD; a.sBg = DD;
        a.sCz = SD;
        a.sbp = (long)H_ * D_; a.sbg = D_;
        gemm_nt<f16, 1, false><<<dim3(4, 16, 2 * NB * GH), 256, 0, stream>>>(a);
      }
      {  // V^T
        GemmArgs a{};
        a.A = wv + (long)h0 * DD; a.Bm = xh + (long)b0 * SD;
        a.C = vT; a.bias = bv + (long)h0 * D_;
        a.K = D_; a.lda = D_; a.ldb = D_; a.ldc = S_;
        a.zbase = 0; a.NG = GH; a.PBG = NB * GH;
        a.sAg = DD;
        a.sBb = SD;
        a.sCz = DS;
        a.sbg = D_;
        gemm_nt<f16, 2, false><<<dim3(16, 4, NB * GH), 256, 0, stream>>>(a);
      }
      for (int g0 = 0; g0 < NB * GH; g0 += GS) {
        hipMemsetAsync(rowmax, 0, (size_t)GS * S_ * 4, stream);
        {  // scores = Q·K^T (f16 out) + fp32 row max
          GemmArgs a{};
          a.A = qk + (long)g0 * SD;
          a.Bm = qk + ((long)NB * GH + g0) * SD;
          a.C = scores; a.Mout = rowmax;
          a.K = D_; a.lda = D_; a.ldb = D_; a.ldc = S_;
          a.zbase = g0; a.NG = GH; a.PBG = NB * GH;
          a.sAz = SD; a.sBz = SD; a.sCz = (long)eSS; a.sMz = S_;
          gemm_nt<f16, 0, true><<<dim3(16, 16, GS), 256, 0, stream>>>(a);
        }
        {  // flash PV (exp-once, 64x256 blocks): catb = softmax(scores)·V
          PvArgs a{};
          a.S = scores; a.M = rowmax; a.V = vT + (long)g0 * DS;
          a.C = catb + (long)h0 * D_;
          a.ldc = H_ * D_; a.zbase = g0; a.NG = GH;
          a.sVz = DS; a.sCb = (long)S_ * H_ * D_; a.sCg = D_;
          pv_flash<<<dim3(2, S_ / 64, GS), 256, 0, stream>>>(a);
        }
      }
    }
    {  // out-proj split-K (2 slabs of 2048)
      GemmArgs a{};
      a.A = catb; a.Bm = wo;
      a.C = opart;
      a.K = 2048; a.lda = H_ * D_; a.ldb = H_ * D_; a.ldc = D_;
      a.zbase = 0; a.NG = 2; a.PBG = NB * 2;
      a.sAb = (long)S_ * H_ * D_; a.sAg = 2048;
      a.sBg = 2048;
      a.sCb = SD; a.sCg = (long)NB * SD;
      gemm_nt<float, 0, false><<<dim3(4, 16, NB * 2), 256, 0, stream>>>(a);
    }
    reduce_out<<<dim3((unsigned)(((long)NB * SD + 255) / 256)), 256, 0, stream>>>(
        opart, bo, out + (long)b0 * SD, (long)NB * SD, 2);
  }
}

// Round 15
// 534.021 us; speedup vs baseline: 3.0159x; 1.0406x over previous
//
#include <hip/hip_runtime.h>

typedef _Float16 f16;
typedef _Float16 f16x8 __attribute__((ext_vector_type(8)));
typedef float f32x4 __attribute__((ext_vector_type(4)));

#define B_ 2
#define S_ 2048
#define D_ 512
#define H_ 8

__device__ inline void async_ld16(const void* g, void* l) {
  __builtin_amdgcn_global_load_lds((__attribute__((address_space(1))) void*)(g),
                                   (__attribute__((address_space(3))) void*)(l),
                                   16, 0, 0);
}

// monotone uint mapping of fp32 for atomicMax-based row max
__device__ inline unsigned fmap(float f) {
  unsigned u = __float_as_uint(f);
  return (u & 0x80000000u) ? ~u : (u | 0x80000000u);
}
__device__ inline float funmap(unsigned k) {
  return (k & 0x80000000u) ? __uint_as_float(k ^ 0x80000000u) : __uint_as_float(~k);
}

__global__ __launch_bounds__(256) void cvt_f16(const float* __restrict__ src,
                                               f16* __restrict__ dst, long n) {
  long i = (long)blockIdx.x * 256 + threadIdx.x;
  if (i >= n) return;
  dst[i] = (f16)src[i];
}

// [z][R][C] fp32 -> [z][C][R] fp16
__global__ __launch_bounds__(256) void transpose_f32(const float* __restrict__ src,
                                                     f16* __restrict__ dst, int R, int C) {
  __shared__ float t[32][33];
  size_t zoff = (size_t)blockIdx.z * R * C;
  const float* s = src + zoff;
  int tx = threadIdx.x;
  int ty = threadIdx.y;
  int c0 = blockIdx.x * 32, r0 = blockIdx.y * 32;
#pragma unroll
  for (int i = 0; i < 4; ++i)
    t[ty + i * 8][tx] = s[(size_t)(r0 + ty + i * 8) * C + c0 + tx];
  __syncthreads();
#pragma unroll
  for (int i = 0; i < 4; ++i)
    dst[zoff + (size_t)(c0 + ty + i * 8) * R + r0 + tx] = (f16)t[tx][ty + i * 8];
}

// out[i] = bo[i%D] + sum over nslab split-K partial slabs
__global__ __launch_bounds__(256) void reduce_out(const float* __restrict__ part,
                                                  const float* __restrict__ bo,
                                                  float* __restrict__ out, long n, int nslab) {
  long i = (long)blockIdx.x * 256 + threadIdx.x;
  if (i >= n) return;
  float v = bo[i & (D_ - 1)];
  for (int s = 0; s < nslab; ++s) v += part[(long)s * n + i];
  out[i] = v;
}

struct GemmArgs {
  const f16 *A, *Bm;
  void* C;
  const float* bias;
  unsigned* Mout;   // PEXP: global row max (mapped)
  float* Mloc;      // PEXP: per-(colblock,row) local max
  int K, lda, ldb, ldc;
  int zbase, NG, PBG;
  long sAp, sAb, sAg, sAz;
  long sBp, sBb, sBg, sBz;
  long sCp, sCb, sCg, sCz;
  long sbp, sbb, sbg, sbz;
  long sMz, sMlz;
};

// NT GEMM fp16, fp32 acc. Swizzle s(r)=(r>>1)&3 (2-way = free; verified r10:
// conflicts 8.4M -> 0). PEXP (flash rescaling): epilogue computes block-local
// row max m_loc over the 128 output cols (shfl + LDS wave-pair exchange),
// stores P = exp(s - m_loc) f16, writes Mloc[cb][row], atomicMax global max.
template <typename OutT, int BIAS, bool PEXP>
__global__ __launch_bounds__(256) void gemm_nt(GemmArgs p) {
  int zloc = blockIdx.z;
  int zi = p.zbase + zloc;
  int pp = zi / p.PBG; int rz = zi - pp * p.PBG;
  int bb = rz / p.NG;  int g = rz - bb * p.NG;
  const f16* A  = p.A + (pp * p.sAp + bb * p.sAb + g * p.sAg + (long)zloc * p.sAz);
  const f16* Bm = p.Bm + (pp * p.sBp + bb * p.sBb + g * p.sBg + (long)zloc * p.sBz);
  OutT* C = (OutT*)p.C + (pp * p.sCp + bb * p.sCb + g * p.sCg + (long)zloc * p.sCz);
  const float* bias = nullptr;
  if (BIAS) bias = p.bias + (pp * p.sbp + bb * p.sbb + g * p.sbg + (long)zloc * p.sbz);
  unsigned* Mz = PEXP ? (p.Mout + (long)zloc * p.sMz) : nullptr;

  __shared__ f16 lA[4096];
  __shared__ f16 lB[4096];
  __shared__ float lMx[PEXP ? 256 : 1];

  int tid = threadIdx.x;
  int lane = tid & 63;
  int w = tid >> 6;
  int wm = (w >> 1) << 6;
  int wn = (w & 1) << 6;
  long bm = (long)blockIdx.y * 128;
  long bn = (long)blockIdx.x * 128;

  f32x4 acc[4][4] = {};
  int qd = lane >> 4;
  int fr = lane & 15;

  int q0 = tid, q1 = tid + 256;
  int r0s = q0 >> 2, c0s = (q0 & 3) ^ ((r0s >> 1) & 3);
  int r1s = q1 >> 2, c1s = (q1 & 3) ^ ((r1s >> 1) & 3);

  for (int k0 = 0; k0 < p.K; k0 += 32) {
    long oa0 = (bm + r0s) * (long)p.lda + (k0 + c0s * 8);
    long oa1 = (bm + r1s) * (long)p.lda + (k0 + c1s * 8);
    long ob0 = (bn + r0s) * (long)p.ldb + (k0 + c0s * 8);
    long ob1 = (bn + r1s) * (long)p.ldb + (k0 + c1s * 8);
    __syncthreads();
    async_ld16(A + oa0,  lA + (size_t)q0 * 8);
    async_ld16(A + oa1,  lA + (size_t)q1 * 8);
    async_ld16(Bm + ob0, lB + (size_t)q0 * 8);
    async_ld16(Bm + ob1, lB + (size_t)q1 * 8);
    __syncthreads();

    f16x8 ah[4], bh[4];
#pragma unroll
    for (int i = 0; i < 4; ++i) {
      int m = wm + i * 16 + fr;
      ah[i] = *(const f16x8*)(lA + ((size_t)m * 4 + (qd ^ ((m >> 1) & 3))) * 8);
      int n = wn + i * 16 + fr;
      bh[i] = *(const f16x8*)(lB + ((size_t)n * 4 + (qd ^ ((n >> 1) & 3))) * 8);
    }
#pragma unroll
    for (int i = 0; i < 4; ++i)
#pragma unroll
      for (int j = 0; j < 4; ++j)
        acc[i][j] = __builtin_amdgcn_mfma_f32_16x16x32_f16(ah[i], bh[j], acc[i][j], 0, 0, 0);
  }

  int rr0 = qd * 4;
  if (PEXP) {
    // wave-local row max over its 64 cols (butterfly over fr), exchange wn-pair
#pragma unroll
    for (int i = 0; i < 4; ++i) {
#pragma unroll
      for (int r = 0; r < 4; ++r) {
        float v = fmaxf(fmaxf(acc[i][0][r], acc[i][1][r]),
                        fmaxf(acc[i][2][r], acc[i][3][r]));
        v = fmaxf(v, __shfl_xor(v, 1, 64));
        v = fmaxf(v, __shfl_xor(v, 2, 64));
        v = fmaxf(v, __shfl_xor(v, 4, 64));
        v = fmaxf(v, __shfl_xor(v, 8, 64));
        if (fr == 0) lMx[(w & 1) * 128 + wm + i * 16 + rr0 + r] = v;
      }
    }
    __syncthreads();
#pragma unroll
    for (int i = 0; i < 4; ++i) {
#pragma unroll
      for (int r = 0; r < 4; ++r) {
        int rl = wm + i * 16 + rr0 + r;
        float ml = fmaxf(lMx[rl], lMx[128 + rl]);
        long row = bm + rl;
#pragma unroll
        for (int j = 0; j < 4; ++j) {
          long col = bn + wn + j * 16 + fr;
          ((f16*)C)[row * (long)p.ldc + col] = (f16)__expf(acc[i][j][r] - ml);
        }
        if ((w & 1) == 0 && fr == 0) {
          p.Mloc[(long)zloc * p.sMlz + (long)blockIdx.x * S_ + row] = ml;
          atomicMax(Mz + row, fmap(ml));
        }
      }
    }
  } else {
#pragma unroll
    for (int i = 0; i < 4; ++i) {
#pragma unroll
      for (int j = 0; j < 4; ++j) {
#pragma unroll
        for (int r = 0; r < 4; ++r) {
          long row = bm + wm + i * 16 + rr0 + r;
          long col = bn + wn + j * 16 + fr;
          float v = acc[i][j][r];
          if (BIAS == 1) v += bias[col];
          if (BIAS == 2) v += bias[row];
          C[row * (long)p.ldc + col] = (OutT)v;
        }
      }
    }
  }
}

// Flash-PV with pre-exp'd P: O = sum_t P_loc[s][t]*alpha(s,cb) * V[e][t] / l[s],
// alpha = exp(m_loc - m_glob) per (row, 128-col block). No exp phase, no lS:
// stage P directly, rescale A-fragments with packed f16 muls; l via ones-MFMA.
// Block = 64 s-rows x 256 e-cols, 20 KB LDS -> 4+ blocks/CU on 1024-block grid.
struct PvArgs {
  const f16* S; const unsigned* M; const float* Ml; const f16* V; f16* C;
  int ldc, zbase, NG;
  long sVz, sCb, sCg;
};
__global__ __launch_bounds__(256) void pv_flash(PvArgs p) {
  int zloc = blockIdx.z;
  int zi = p.zbase + zloc;
  int bb = zi / p.NG; int g = zi - bb * p.NG;
  const f16* Sm = p.S + (long)zloc * S_ * S_;
  const unsigned* Mz = p.M + (long)zloc * S_;
  const float* Ml = p.Ml + (long)zloc * 16 * S_;
  const f16* V = p.V + (long)zloc * p.sVz;
  f16* C = p.C + bb * p.sCb + g * p.sCg;

  __shared__ f16 lP[64 * 32];    // staged P (A-fragment layout) 4 KB
  __shared__ f16 lV[256 * 32];   // V tile (B-fragment layout) 16 KB

  int tid = threadIdx.x;
  int lane = tid & 63;
  int w = tid >> 6;
  long bm = (long)blockIdx.y * 64;   // s-row origin
  long bn = (long)blockIdx.x * 256;  // e origin of the block
  int e0 = w << 6;                   // wave's 64-col e origin within block

  int qd = lane >> 4;
  int fr = lane & 15;

  f32x4 acc[4][4] = {};
  f32x4 lacc[4] = {};
  f16x8 ones;
#pragma unroll
  for (int j = 0; j < 8; ++j) ones[j] = (f16)1.0f;

  float mg[4];
#pragma unroll
  for (int i = 0; i < 4; ++i) mg[i] = funmap(Mz[bm + i * 16 + fr]);
  f16 al16[4];

  int rs = tid >> 2, cs = (tid & 3) ^ ((rs >> 1) & 3);  // P staging map

  for (int k0 = 0; k0 < S_; k0 += 32) {
    if ((k0 & 127) == 0) {  // new 128-col scores block: refresh alpha
      int cb = k0 >> 7;
#pragma unroll
      for (int i = 0; i < 4; ++i)
        al16[i] = (f16)__expf(Ml[cb * S_ + bm + i * 16 + fr] - mg[i]);
    }
    __syncthreads();  // prior fragment reads done
    async_ld16(Sm + (bm + rs) * (long)S_ + (k0 + cs * 8), lP + (size_t)tid * 8);
#pragma unroll
    for (int j = 0; j < 4; ++j) {
      int q = j * 256 + tid;
      int rv = q >> 2, cv = (q & 3) ^ ((rv >> 1) & 3);
      async_ld16(V + (bn + rv) * (long)S_ + (k0 + cv * 8), lV + (size_t)q * 8);
    }
    __syncthreads();  // staged

    f16x8 ah[4], bh[4];
#pragma unroll
    for (int i = 0; i < 4; ++i) {
      int m = i * 16 + fr;
      ah[i] = *(const f16x8*)(lP + ((size_t)m * 4 + (qd ^ ((m >> 1) & 3))) * 8);
#pragma unroll
      for (int j = 0; j < 8; ++j) ah[i][j] *= al16[i];
    }
#pragma unroll
    for (int j = 0; j < 4; ++j) {
      int n = e0 + j * 16 + fr;
      bh[j] = *(const f16x8*)(lV + ((size_t)n * 4 + (qd ^ ((n >> 1) & 3))) * 8);
    }
#pragma unroll
    for (int i = 0; i < 4; ++i) {
      lacc[i] = __builtin_amdgcn_mfma_f32_16x16x32_f16(ah[i], ones, lacc[i], 0, 0, 0);
#pragma unroll
      for (int j = 0; j < 4; ++j)
        acc[i][j] = __builtin_amdgcn_mfma_f32_16x16x32_f16(ah[i], bh[j], acc[i][j], 0, 0, 0);
    }
  }

  int rr0 = (lane >> 4) * 4;
#pragma unroll
  for (int i = 0; i < 4; ++i) {
    float inv[4];
#pragma unroll
    for (int r = 0; r < 4; ++r) inv[r] = 1.0f / lacc[i][r];
#pragma unroll
    for (int j = 0; j < 4; ++j) {
#pragma unroll
      for (int r = 0; r < 4; ++r) {
        long row = bm + i * 16 + rr0 + r;
        long col = bn + e0 + j * 16 + fr;
        C[row * (long)p.ldc + col] = (f16)(acc[i][j][r] * inv[r]);
      }
    }
  }
}

extern "C" void kernel_launch(void* const* d_in, const int* in_sizes, int n_in,
                              void* d_out, int out_size, void* d_ws, size_t ws_size,
                              hipStream_t stream) {
  const float* x  = (const float*)d_in[0];
  const float* Wq = (const float*)d_in[1];
  const float* bq = (const float*)d_in[2];
  const float* Wk = (const float*)d_in[3];
  const float* bk = (const float*)d_in[4];
  const float* Wv = (const float*)d_in[5];
  const float* bv = (const float*)d_in[6];
  const float* Wo = (const float*)d_in[7];
  const float* bo = (const float*)d_in[8];
  float* out = (float*)d_out;

  auto al = [](size_t v) { return (v + 255) & ~(size_t)255; };
  const size_t eX = (size_t)B_ * S_ * D_;
  const size_t eW = (size_t)H_ * D_ * D_;
  const size_t eSS = (size_t)S_ * S_;
  const long SD = (long)S_ * D_;
  const long DD = (long)D_ * D_;
  const long DS = (long)D_ * S_;

  size_t fixed = al(eX * 2) + al(2 * eW * 2) + al(eW * 2) + al(eW * 2)
               + al(2ULL * H_ * D_ * 4);
  int NB = 1, GH = 1, GS = 1; bool found = false;
  for (int nb = 2; nb >= 1 && !found; --nb)
    for (int gh = 8; gh >= 1 && !found; gh >>= 1)
      for (int gs = nb * gh; gs >= 1 && !found; gs >>= 1) {
        size_t need = fixed + al((size_t)nb * S_ * H_ * D_ * 2)
                    + al(2ULL * nb * gh * S_ * D_ * 2)
                    + al((size_t)nb * gh * D_ * S_ * 2)
                    + al(2ULL * nb * SD * 4)
                    + al((size_t)gs * eSS * 2) + al((size_t)gs * S_ * 4)
                    + al((size_t)gs * 16 * S_ * 4);
        if (need <= ws_size) { NB = nb; GH = gh; GS = gs; found = true; }
      }

  char* p0 = (char*)d_ws;
  size_t off = 0;
  f16* xh    = (f16*)(p0 + off); off += al(eX * 2);
  f16* wqk   = (f16*)(p0 + off); off += al(2 * eW * 2);
  f16* wv    = (f16*)(p0 + off); off += al(eW * 2);
  f16* wo    = (f16*)(p0 + off); off += al(eW * 2);
  float* bqk = (float*)(p0 + off); off += al(2ULL * H_ * D_ * 4);
  f16* catb  = (f16*)(p0 + off); off += al((size_t)NB * S_ * H_ * D_ * 2);
  f16* qk    = (f16*)(p0 + off); off += al(2ULL * NB * GH * S_ * D_ * 2);
  f16* vT    = (f16*)(p0 + off); off += al((size_t)NB * GH * D_ * S_ * 2);
  float* opart = (float*)(p0 + off); off += al(2ULL * NB * SD * 4);
  f16* scores = (f16*)(p0 + off); off += al((size_t)GS * eSS * 2);
  unsigned* rowmax = (unsigned*)(p0 + off); off += al((size_t)GS * S_ * 4);
  float* mloc = (float*)(p0 + off);

  // ---- prep ----
  cvt_f16<<<dim3((unsigned)((eX + 255) / 256)), 256, 0, stream>>>(x, xh, (long)eX);
  dim3 tb(32, 8, 1);
  transpose_f32<<<dim3(16, 16, H_), tb, 0, stream>>>(Wq, wqk, D_, D_);
  transpose_f32<<<dim3(16, 16, H_), tb, 0, stream>>>(Wk, wqk + eW, D_, D_);
  transpose_f32<<<dim3(16, 16, H_), tb, 0, stream>>>(Wv, wv, D_, D_);
  transpose_f32<<<dim3(16, 128, 1), tb, 0, stream>>>(Wo, wo, H_ * D_, D_);
  hipMemcpyAsync(bqk, bq, (size_t)H_ * D_ * 4, hipMemcpyDeviceToDevice, stream);
  hipMemcpyAsync(bqk + H_ * D_, bk, (size_t)H_ * D_ * 4, hipMemcpyDeviceToDevice, stream);

  for (int b0 = 0; b0 < B_; b0 += NB) {
    for (int h0 = 0; h0 < H_; h0 += GH) {
      {  // Q+K projections
        GemmArgs a{};
        a.A = xh + (long)b0 * SD;
        a.Bm = wqk + (long)h0 * DD;
        a.C = qk; a.bias = bqk + (long)h0 * D_;
        a.K = D_; a.lda = D_; a.ldb = D_; a.ldc = D_;
        a.zbase = 0; a.NG = GH; a.PBG = NB * GH;
        a.sAb = SD;
        a.sBp = (long)H_ * DD; a.sBg = DD;
        a.sCz = SD;
        a.sbp = (long)H_ * D_; a.sbg = D_;
        gemm_nt<f16, 1, false><<<dim3(4, 16, 2 * NB * GH), 256, 0, stream>>>(a);
      }
      {  // V^T
        GemmArgs a{};
        a.A = wv + (long)h0 * DD; a.Bm = xh + (long)b0 * SD;
        a.C = vT; a.bias = bv + (long)h0 * D_;
        a.K = D_; a.lda = D_; a.ldb = D_; a.ldc = S_;
        a.zbase = 0; a.NG = GH; a.PBG = NB * GH;
        a.sAg = DD;
        a.sBb = SD;
        a.sCz = DS;
        a.sbg = D_;
        gemm_nt<f16, 2, false><<<dim3(16, 4, NB * GH), 256, 0, stream>>>(a);
      }
      for (int g0 = 0; g0 < NB * GH; g0 += GS) {
        hipMemsetAsync(rowmax, 0, (size_t)GS * S_ * 4, stream);
        {  // scores -> P_loc = exp(s - m_loc) f16, Mloc, global rowmax
          GemmArgs a{};
          a.A = qk + (long)g0 * SD;
          a.Bm = qk + ((long)NB * GH + g0) * SD;
          a.C = scores; a.Mout = rowmax; a.Mloc = mloc;
          a.K = D_; a.lda = D_; a.ldb = D_; a.ldc = S_;
          a.zbase = g0; a.NG = GH; a.PBG = NB * GH;
          a.sAz = SD; a.sBz = SD; a.sCz = (long)eSS; a.sMz = S_;
          a.sMlz = 16L * S_;
          gemm_nt<f16, 0, true><<<dim3(16, 16, GS), 256, 0, stream>>>(a);
        }
        {  // flash PV (rescale-only): catb = P·V / l
          PvArgs a{};
          a.S = scores; a.M = rowmax; a.Ml = mloc; a.V = vT + (long)g0 * DS;
          a.C = catb + (long)h0 * D_;
          a.ldc = H_ * D_; a.zbase = g0; a.NG = GH;
          a.sVz = DS; a.sCb = (long)S_ * H_ * D_; a.sCg = D_;
          pv_flash<<<dim3(2, S_ / 64, GS), 256, 0, stream>>>(a);
        }
      }
    }
    {  // out-proj split-K (2 slabs of 2048)
      GemmArgs a{};
      a.A = catb; a.Bm = wo;
      a.C = opart;
      a.K = 2048; a.lda = H_ * D_; a.ldb = H_ * D_; a.ldc = D_;
      a.zbase = 0; a.NG = 2; a.PBG = NB * 2;
      a.sAb = (long)S_ * H_ * D_; a.sAg = 2048;
      a.sBg = 2048;
      a.sCb = SD; a.sCg = (long)NB * SD;
      gemm_nt<float, 0, false><<<dim3(4, 16, NB * 2), 256, 0, stream>>>(a);
    }
    reduce_out<<<dim3((unsigned)(((long)NB * SD + 255) / 256)), 256, 0, stream>>>(
        opart, bo, out + (long)b0 * SD, (long)NB * SD, 2);
  }
}

// Round 16
// 520.815 us; speedup vs baseline: 3.0924x; 1.0254x over previous
//
#include <hip/hip_runtime.h>

typedef _Float16 f16;
typedef _Float16 f16x8 __attribute__((ext_vector_type(8)));
typedef float f32x4 __attribute__((ext_vector_type(4)));

#define B_ 2
#define S_ 2048
#define D_ 512
#define H_ 8

__device__ inline void async_ld16(const void* g, void* l) {
  __builtin_amdgcn_global_load_lds((__attribute__((address_space(1))) void*)(g),
                                   (__attribute__((address_space(3))) void*)(l),
                                   16, 0, 0);
}

// monotone uint mapping of fp32 for atomicMax-based row max
__device__ inline unsigned fmap(float f) {
  unsigned u = __float_as_uint(f);
  return (u & 0x80000000u) ? ~u : (u | 0x80000000u);
}
__device__ inline float funmap(unsigned k) {
  return (k & 0x80000000u) ? __uint_as_float(k ^ 0x80000000u) : __uint_as_float(~k);
}

__global__ __launch_bounds__(256) void cvt_f16(const float* __restrict__ src,
                                               f16* __restrict__ dst, long n) {
  long i = (long)blockIdx.x * 256 + threadIdx.x;
  if (i >= n) return;
  dst[i] = (f16)src[i];
}

// [z][R][C] fp32 -> [z][C][R] fp16
__global__ __launch_bounds__(256) void transpose_f32(const float* __restrict__ src,
                                                     f16* __restrict__ dst, int R, int C) {
  __shared__ float t[32][33];
  size_t zoff = (size_t)blockIdx.z * R * C;
  const float* s = src + zoff;
  int tx = threadIdx.x;
  int ty = threadIdx.y;
  int c0 = blockIdx.x * 32, r0 = blockIdx.y * 32;
#pragma unroll
  for (int i = 0; i < 4; ++i)
    t[ty + i * 8][tx] = s[(size_t)(r0 + ty + i * 8) * C + c0 + tx];
  __syncthreads();
#pragma unroll
  for (int i = 0; i < 4; ++i)
    dst[zoff + (size_t)(c0 + ty + i * 8) * R + r0 + tx] = (f16)t[tx][ty + i * 8];
}

// out[i] = bo[i%D] + sum over nslab split-K partial slabs
__global__ __launch_bounds__(256) void reduce_out(const float* __restrict__ part,
                                                  const float* __restrict__ bo,
                                                  float* __restrict__ out, long n, int nslab) {
  long i = (long)blockIdx.x * 256 + threadIdx.x;
  if (i >= n) return;
  float v = bo[i & (D_ - 1)];
  for (int s = 0; s < nslab; ++s) v += part[(long)s * n + i];
  out[i] = v;
}

struct GemmArgs {
  const f16 *A, *Bm;
  void* C;
  const float* bias;
  unsigned* Mout;   // PEXP: global row max (mapped)
  float* Mloc;      // PEXP: per-(colblock,row) local max
  int K, lda, ldb, ldc;
  int zbase, NG, PBG;
  long sAp, sAb, sAg, sAz;
  long sBp, sBb, sBg, sBz;
  long sCp, sCb, sCg, sCz;
  long sbp, sbb, sbg, sbz;
  long sMz, sMlz;
};

// NT GEMM fp16, fp32 acc. Swizzle s(r)=(r>>1)&3 (2-way = free; verified r10).
// PEXP (flash rescaling): epilogue computes block-local row max m_loc, stores
// P = exp(s - m_loc) f16 via LDS repack -> f16x8 coalesced stores (r15's
// per-element 2B scatter stores were the VALUBusy=44% bottleneck), writes
// Mloc[cb][row], atomicMax global max.
template <typename OutT, int BIAS, bool PEXP>
__global__ __launch_bounds__(256) void gemm_nt(GemmArgs p) {
  int zloc = blockIdx.z;
  int zi = p.zbase + zloc;
  int pp = zi / p.PBG; int rz = zi - pp * p.PBG;
  int bb = rz / p.NG;  int g = rz - bb * p.NG;
  const f16* A  = p.A + (pp * p.sAp + bb * p.sAb + g * p.sAg + (long)zloc * p.sAz);
  const f16* Bm = p.Bm + (pp * p.sBp + bb * p.sBb + g * p.sBg + (long)zloc * p.sBz);
  OutT* C = (OutT*)p.C + (pp * p.sCp + bb * p.sCb + g * p.sCg + (long)zloc * p.sCz);
  const float* bias = nullptr;
  if (BIAS) bias = p.bias + (pp * p.sbp + bb * p.sbb + g * p.sbg + (long)zloc * p.sbz);
  unsigned* Mz = PEXP ? (p.Mout + (long)zloc * p.sMz) : nullptr;

  __shared__ f16 lA[4096];
  __shared__ f16 lB[4096];
  __shared__ float lMx[PEXP ? 256 : 1];
  __shared__ f16 lR[PEXP ? 32 * 136 : 1];  // repack buffer, +8 pad/row

  int tid = threadIdx.x;
  int lane = tid & 63;
  int w = tid >> 6;
  int wm = (w >> 1) << 6;
  int wn = (w & 1) << 6;
  long bm = (long)blockIdx.y * 128;
  long bn = (long)blockIdx.x * 128;

  f32x4 acc[4][4] = {};
  int qd = lane >> 4;
  int fr = lane & 15;

  int q0 = tid, q1 = tid + 256;
  int r0s = q0 >> 2, c0s = (q0 & 3) ^ ((r0s >> 1) & 3);
  int r1s = q1 >> 2, c1s = (q1 & 3) ^ ((r1s >> 1) & 3);

  for (int k0 = 0; k0 < p.K; k0 += 32) {
    long oa0 = (bm + r0s) * (long)p.lda + (k0 + c0s * 8);
    long oa1 = (bm + r1s) * (long)p.lda + (k0 + c1s * 8);
    long ob0 = (bn + r0s) * (long)p.ldb + (k0 + c0s * 8);
    long ob1 = (bn + r1s) * (long)p.ldb + (k0 + c1s * 8);
    __syncthreads();
    async_ld16(A + oa0,  lA + (size_t)q0 * 8);
    async_ld16(A + oa1,  lA + (size_t)q1 * 8);
    async_ld16(Bm + ob0, lB + (size_t)q0 * 8);
    async_ld16(Bm + ob1, lB + (size_t)q1 * 8);
    __syncthreads();

    f16x8 ah[4], bh[4];
#pragma unroll
    for (int i = 0; i < 4; ++i) {
      int m = wm + i * 16 + fr;
      ah[i] = *(const f16x8*)(lA + ((size_t)m * 4 + (qd ^ ((m >> 1) & 3))) * 8);
      int n = wn + i * 16 + fr;
      bh[i] = *(const f16x8*)(lB + ((size_t)n * 4 + (qd ^ ((n >> 1) & 3))) * 8);
    }
#pragma unroll
    for (int i = 0; i < 4; ++i)
#pragma unroll
      for (int j = 0; j < 4; ++j)
        acc[i][j] = __builtin_amdgcn_mfma_f32_16x16x32_f16(ah[i], bh[j], acc[i][j], 0, 0, 0);
  }

  int rr0 = qd * 4;
  if (PEXP) {
    // wave-local row max over its 64 cols -> lMx[wn-half][row]
#pragma unroll
    for (int i = 0; i < 4; ++i) {
#pragma unroll
      for (int r = 0; r < 4; ++r) {
        float v = fmaxf(fmaxf(acc[i][0][r], acc[i][1][r]),
                        fmaxf(acc[i][2][r], acc[i][3][r]));
        v = fmaxf(v, __shfl_xor(v, 1, 64));
        v = fmaxf(v, __shfl_xor(v, 2, 64));
        v = fmaxf(v, __shfl_xor(v, 4, 64));
        v = fmaxf(v, __shfl_xor(v, 8, 64));
        if (fr == 0) lMx[(w & 1) * 128 + wm + i * 16 + rr0 + r] = v;
      }
    }
    __syncthreads();
    if (tid < 128) {  // Mloc + global rowmax, one thread per row
      float ml = fmaxf(lMx[tid], lMx[128 + tid]);
      long row = bm + tid;
      p.Mloc[(long)zloc * p.sMlz + (long)blockIdx.x * S_ + row] = ml;
      atomicMax(Mz + row, fmap(ml));
    }
    int rowBase = (w >> 1) << 4;  // wm half -> 0 or 16
#pragma unroll
    for (int i = 0; i < 4; ++i) {
      __syncthreads();  // lR free
#pragma unroll
      for (int r = 0; r < 4; ++r) {
        int rl = wm + i * 16 + rr0 + r;
        float ml = fmaxf(lMx[rl], lMx[128 + rl]);
        int rowLoc = rowBase + rr0 + r;  // 0..31
#pragma unroll
        for (int j = 0; j < 4; ++j) {
          int col = wn + j * 16 + fr;
          lR[rowLoc * 136 + col] = (f16)__expf(acc[i][j][r] - ml);
        }
      }
      __syncthreads();  // lR ready
      int rowLoc = tid >> 3;
      int colLoc = (tid & 7) * 16;
      long grow = bm + ((rowLoc & 15) + i * 16) + ((long)(rowLoc >> 4) << 6);
      f16x8 v0 = *(const f16x8*)(lR + rowLoc * 136 + colLoc);
      f16x8 v1 = *(const f16x8*)(lR + rowLoc * 136 + colLoc + 8);
      f16* dst = (f16*)C + grow * (long)p.ldc + bn + colLoc;
      *(f16x8*)(dst) = v0;
      *(f16x8*)(dst + 8) = v1;
    }
  } else {
#pragma unroll
    for (int i = 0; i < 4; ++i) {
#pragma unroll
      for (int j = 0; j < 4; ++j) {
#pragma unroll
        for (int r = 0; r < 4; ++r) {
          long row = bm + wm + i * 16 + rr0 + r;
          long col = bn + wn + j * 16 + fr;
          float v = acc[i][j][r];
          if (BIAS == 1) v += bias[col];
          if (BIAS == 2) v += bias[row];
          C[row * (long)p.ldc + col] = (OutT)v;
        }
      }
    }
  }
}

// Flash-PV with pre-exp'd P: O = sum_t P_loc[s][t]*alpha(s,cb) * V[e][t] / l[s],
// alpha = exp(m_loc - m_glob) per (row, 128-col block). Stage P directly,
// rescale A-fragments with packed f16 muls; l via ones-MFMA.
struct PvArgs {
  const f16* S; const unsigned* M; const float* Ml; const f16* V; f16* C;
  int ldc, zbase, NG;
  long sVz, sCb, sCg;
};
__global__ __launch_bounds__(256) void pv_flash(PvArgs p) {
  int zloc = blockIdx.z;
  int zi = p.zbase + zloc;
  int bb = zi / p.NG; int g = zi - bb * p.NG;
  const f16* Sm = p.S + (long)zloc * S_ * S_;
  const unsigned* Mz = p.M + (long)zloc * S_;
  const float* Ml = p.Ml + (long)zloc * 16 * S_;
  const f16* V = p.V + (long)zloc * p.sVz;
  f16* C = p.C + bb * p.sCb + g * p.sCg;

  __shared__ f16 lP[64 * 32];    // staged P (A-fragment layout) 4 KB
  __shared__ f16 lV[256 * 32];   // V tile (B-fragment layout) 16 KB

  int tid = threadIdx.x;
  int lane = tid & 63;
  int w = tid >> 6;
  long bm = (long)blockIdx.y * 64;   // s-row origin
  long bn = (long)blockIdx.x * 256;  // e origin of the block
  int e0 = w << 6;                   // wave's 64-col e origin within block

  int qd = lane >> 4;
  int fr = lane & 15;

  f32x4 acc[4][4] = {};
  f32x4 lacc[4] = {};
  f16x8 ones;
#pragma unroll
  for (int j = 0; j < 8; ++j) ones[j] = (f16)1.0f;

  float mg[4];
#pragma unroll
  for (int i = 0; i < 4; ++i) mg[i] = funmap(Mz[bm + i * 16 + fr]);
  f16 al16[4];

  int rs = tid >> 2, cs = (tid & 3) ^ ((rs >> 1) & 3);  // P staging map

  for (int k0 = 0; k0 < S_; k0 += 32) {
    if ((k0 & 127) == 0) {  // new 128-col scores block: refresh alpha
      int cb = k0 >> 7;
#pragma unroll
      for (int i = 0; i < 4; ++i)
        al16[i] = (f16)__expf(Ml[cb * S_ + bm + i * 16 + fr] - mg[i]);
    }
    __syncthreads();  // prior fragment reads done
    async_ld16(Sm + (bm + rs) * (long)S_ + (k0 + cs * 8), lP + (size_t)tid * 8);
#pragma unroll
    for (int j = 0; j < 4; ++j) {
      int q = j * 256 + tid;
      int rv = q >> 2, cv = (q & 3) ^ ((rv >> 1) & 3);
      async_ld16(V + (bn + rv) * (long)S_ + (k0 + cv * 8), lV + (size_t)q * 8);
    }
    __syncthreads();  // staged

    f16x8 ah[4], bh[4];
#pragma unroll
    for (int i = 0; i < 4; ++i) {
      int m = i * 16 + fr;
      ah[i] = *(const f16x8*)(lP + ((size_t)m * 4 + (qd ^ ((m >> 1) & 3))) * 8);
#pragma unroll
      for (int j = 0; j < 8; ++j) ah[i][j] *= al16[i];
    }
#pragma unroll
    for (int j = 0; j < 4; ++j) {
      int n = e0 + j * 16 + fr;
      bh[j] = *(const f16x8*)(lV + ((size_t)n * 4 + (qd ^ ((n >> 1) & 3))) * 8);
    }
#pragma unroll
    for (int i = 0; i < 4; ++i) {
      lacc[i] = __builtin_amdgcn_mfma_f32_16x16x32_f16(ah[i], ones, lacc[i], 0, 0, 0);
#pragma unroll
      for (int j = 0; j < 4; ++j)
        acc[i][j] = __builtin_amdgcn_mfma_f32_16x16x32_f16(ah[i], bh[j], acc[i][j], 0, 0, 0);
    }
  }

  int rr0 = (lane >> 4) * 4;
#pragma unroll
  for (int i = 0; i < 4; ++i) {
    float inv[4];
#pragma unroll
    for (int r = 0; r < 4; ++r) inv[r] = 1.0f / lacc[i][r];
#pragma unroll
    for (int j = 0; j < 4; ++j) {
#pragma unroll
      for (int r = 0; r < 4; ++r) {
        long row = bm + i * 16 + rr0 + r;
        long col = bn + e0 + j * 16 + fr;
        C[row * (long)p.ldc + col] = (f16)(acc[i][j][r] * inv[r]);
      }
    }
  }
}

extern "C" void kernel_launch(void* const* d_in, const int* in_sizes, int n_in,
                              void* d_out, int out_size, void* d_ws, size_t ws_size,
                              hipStream_t stream) {
  const float* x  = (const float*)d_in[0];
  const float* Wq = (const float*)d_in[1];
  const float* bq = (const float*)d_in[2];
  const float* Wk = (const float*)d_in[3];
  const float* bk = (const float*)d_in[4];
  const float* Wv = (const float*)d_in[5];
  const float* bv = (const float*)d_in[6];
  const float* Wo = (const float*)d_in[7];
  const float* bo = (const float*)d_in[8];
  float* out = (float*)d_out;

  auto al = [](size_t v) { return (v + 255) & ~(size_t)255; };
  const size_t eX = (size_t)B_ * S_ * D_;
  const size_t eW = (size_t)H_ * D_ * D_;
  const size_t eSS = (size_t)S_ * S_;
  const long SD = (long)S_ * D_;
  const long DD = (long)D_ * D_;
  const long DS = (long)D_ * S_;

  size_t fixed = al(eX * 2) + al(2 * eW * 2) + al(eW * 2) + al(eW * 2)
               + al(2ULL * H_ * D_ * 4);
  int NB = 1, GH = 1, GS = 1; bool found = false;
  for (int nb = 2; nb >= 1 && !found; --nb)
    for (int gh = 8; gh >= 1 && !found; gh >>= 1)
      for (int gs = nb * gh; gs >= 1 && !found; gs >>= 1) {
        size_t need = fixed + al((size_t)nb * S_ * H_ * D_ * 2)
                    + al(2ULL * nb * gh * S_ * D_ * 2)
                    + al((size_t)nb * gh * D_ * S_ * 2)
                    + al(4ULL * nb * SD * 4)
                    + al((size_t)gs * eSS * 2) + al((size_t)gs * S_ * 4)
                    + al((size_t)gs * 16 * S_ * 4);
        if (need <= ws_size) { NB = nb; GH = gh; GS = gs; found = true; }
      }

  char* p0 = (char*)d_ws;
  size_t off = 0;
  f16* xh    = (f16*)(p0 + off); off += al(eX * 2);
  f16* wqk   = (f16*)(p0 + off); off += al(2 * eW * 2);
  f16* wv    = (f16*)(p0 + off); off += al(eW * 2);
  f16* wo    = (f16*)(p0 + off); off += al(eW * 2);
  float* bqk = (float*)(p0 + off); off += al(2ULL * H_ * D_ * 4);
  f16* catb  = (f16*)(p0 + off); off += al((size_t)NB * S_ * H_ * D_ * 2);
  f16* qk    = (f16*)(p0 + off); off += al(2ULL * NB * GH * S_ * D_ * 2);
  f16* vT    = (f16*)(p0 + off); off += al((size_t)NB * GH * D_ * S_ * 2);
  float* opart = (float*)(p0 + off); off += al(4ULL * NB * SD * 4);
  f16* scores = (f16*)(p0 + off); off += al((size_t)GS * eSS * 2);
  unsigned* rowmax = (unsigned*)(p0 + off); off += al((size_t)GS * S_ * 4);
  float* mloc = (float*)(p0 + off);

  // ---- prep ----
  cvt_f16<<<dim3((unsigned)((eX + 255) / 256)), 256, 0, stream>>>(x, xh, (long)eX);
  dim3 tb(32, 8, 1);
  transpose_f32<<<dim3(16, 16, H_), tb, 0, stream>>>(Wq, wqk, D_, D_);
  transpose_f32<<<dim3(16, 16, H_), tb, 0, stream>>>(Wk, wqk + eW, D_, D_);
  transpose_f32<<<dim3(16, 16, H_), tb, 0, stream>>>(Wv, wv, D_, D_);
  transpose_f32<<<dim3(16, 128, 1), tb, 0, stream>>>(Wo, wo, H_ * D_, D_);
  hipMemcpyAsync(bqk, bq, (size_t)H_ * D_ * 4, hipMemcpyDeviceToDevice, stream);
  hipMemcpyAsync(bqk + H_ * D_, bk, (size_t)H_ * D_ * 4, hipMemcpyDeviceToDevice, stream);

  for (int b0 = 0; b0 < B_; b0 += NB) {
    for (int h0 = 0; h0 < H_; h0 += GH) {
      {  // Q+K projections
        GemmArgs a{};
        a.A = xh + (long)b0 * SD;
        a.Bm = wqk + (long)h0 * DD;
        a.C = qk; a.bias = bqk + (long)h0 * D_;
        a.K = D_; a.lda = D_; a.ldb = D_; a.ldc = D_;
        a.zbase = 0; a.NG = GH; a.PBG = NB * GH;
        a.sAb = SD;
        a.sBp = (long)H_ * DD; a.sBg = DD;
        a.sCz = SD;
        a.sbp = (long)H_ * D_; a.sbg = D_;
        gemm_nt<f16, 1, false><<<dim3(4, 16, 2 * NB * GH), 256, 0, stream>>>(a);
      }
      {  // V^T
        GemmArgs a{};
        a.A = wv + (long)h0 * DD; a.Bm = xh + (long)b0 * SD;
        a.C = vT; a.bias = bv + (long)h0 * D_;
        a.K = D_; a.lda = D_; a.ldb = D_; a.ldc = S_;
        a.zbase = 0; a.NG = GH; a.PBG = NB * GH;
        a.sAg = DD;
        a.sBb = SD;
        a.sCz = DS;
        a.sbg = D_;
        gemm_nt<f16, 2, false><<<dim3(16, 4, NB * GH), 256, 0, stream>>>(a);
      }
      for (int g0 = 0; g0 < NB * GH; g0 += GS) {
        hipMemsetAsync(rowmax, 0, (size_t)GS * S_ * 4, stream);
        {  // scores -> P_loc = exp(s - m_loc) f16 (vectorized), Mloc, rowmax
          GemmArgs a{};
          a.A = qk + (long)g0 * SD;
          a.Bm = qk + ((long)NB * GH + g0) * SD;
          a.C = scores; a.Mout = rowmax; a.Mloc = mloc;
          a.K = D_; a.lda = D_; a.ldb = D_; a.ldc = S_;
          a.zbase = g0; a.NG = GH; a.PBG = NB * GH;
          a.sAz = SD; a.sBz = SD; a.sCz = (long)eSS; a.sMz = S_;
          a.sMlz = 16L * S_;
          gemm_nt<f16, 0, true><<<dim3(16, 16, GS), 256, 0, stream>>>(a);
        }
        {  // flash PV (rescale-only): catb = P·V / l
          PvArgs a{};
          a.S = scores; a.M = rowmax; a.Ml = mloc; a.V = vT + (long)g0 * DS;
          a.C = catb + (long)h0 * D_;
          a.ldc = H_ * D_; a.zbase = g0; a.NG = GH;
          a.sVz = DS; a.sCb = (long)S_ * H_ * D_; a.sCg = D_;
          pv_flash<<<dim3(2, S_ / 64, GS), 256, 0, stream>>>(a);
        }
      }
    }
    {  // out-proj split-K (4 slabs of 1024 -> 512 blocks, 2/CU)
      GemmArgs a{};
      a.A = catb; a.Bm = wo;
      a.C = opart;
      a.K = 1024; a.lda = H_ * D_; a.ldb = H_ * D_; a.ldc = D_;
      a.zbase = 0; a.NG = 4; a.PBG = NB * 4;
      a.sAb = (long)S_ * H_ * D_; a.sAg = 1024;
      a.sBg = 1024;
      a.sCb = SD; a.sCg = (long)NB * SD;
      gemm_nt<float, 0, false><<<dim3(4, 16, NB * 4), 256, 0, stream>>>(a);
    }
    reduce_out<<<dim3((unsigned)(((long)NB * SD + 255) / 256)), 256, 0, stream>>>(
        opart, bo, out + (long)b0 * SD, (long)NB * SD, 4);
  }
}